// Round 3
// baseline (272.747 us; speedup 1.0000x reference)
//
#include <hip/hip_runtime.h>
#include <hip/hip_fp16.h>

// GCN encoder: 3x GCNConv (+self-loops, sym deg^-1/2 norm) + ELU + mean-pool.
// N=50000, E=800000, IN=128, HID=64, ZDIM=64, G=64. f32 in/out.
// R7: CSR gather. R8: parallel scan. R9: fp16 gathered operands.
// R11: atomic-free fill. R12/13: fused pool. R15: 8 rows in flight -> 252.6.
// R16: algebraic restructure S(hW)=(Sh)W -> one shared 64-dim gather. 249.6.
// R17: MLP gather decomposition, 32 rows in flight/wave -> 238.1. Partial
//     hit => memory subsystem (not per-wave MLP) is the gather limiter:
//     6.4MB gathered buffer > 4MiB per-XCD L2 -> random 128B fetches served
//     by LLC.
// R18: XCD-LOCAL SPLIT GATHER. Feature dim split into two 32-dim fp16
//     half-buffers (3.2MB each, fits per-XCD L2). Wave = (node, half);
//     half chosen from blockIdx so XCDs 0-3 read only half A, 4-7 only
//     half B (under bid%8 round-robin XCD dispatch; coverage is bid-based
//     => always correct even if mapping differs). 64B rows -> 4 lanes/row,
//     16 groups/wave, 2 preloaded batches = 32 rows in flight (same MLP).

#define IN_DIM 128
#define HID 64
#define ZDIM 64
#define N_GRAPHS 64
#define SCAN_B 1024

__device__ __forceinline__ float elu1(float x) {
    return x > 0.f ? x : expm1f(x);
}

// Accumulate 8 fp16 (held in a float4 raw register) with mask MV into acc[8].
#define ACC8(RV, MV) do { \
    const __half2* _hp = (const __half2*)&(RV); \
    float2 _f0 = __half22float2(_hp[0]); \
    float2 _f1 = __half22float2(_hp[1]); \
    float2 _f2 = __half22float2(_hp[2]); \
    float2 _f3 = __half22float2(_hp[3]); \
    acc[0] = fmaf((MV), _f0.x, acc[0]); \
    acc[1] = fmaf((MV), _f0.y, acc[1]); \
    acc[2] = fmaf((MV), _f1.x, acc[2]); \
    acc[3] = fmaf((MV), _f1.y, acc[3]); \
    acc[4] = fmaf((MV), _f2.x, acc[4]); \
    acc[5] = fmaf((MV), _f2.y, acc[5]); \
    acc[6] = fmaf((MV), _f3.x, acc[6]); \
    acc[7] = fmaf((MV), _f3.y, acc[7]); \
  } while (0)

// rank[e] = within-dst arrival index; kc[d] ends as deg(d).
__global__ void k_count(const int* __restrict__ dst, int* __restrict__ kc,
                        int* __restrict__ rank, int E) {
    int e = blockIdx.x * blockDim.x + threadIdx.x;
    if (e < E) rank[e] = atomicAdd(&kc[dst[e]], 1);
}

// S1: per-block sum of kc -> bsum[blk]
__global__ __launch_bounds__(SCAN_B) void k_scan1(const int* __restrict__ kc,
                                                  int* __restrict__ bsum, int n) {
    __shared__ int wpart[16];
    int tid = threadIdx.x, lane = tid & 63, w = tid >> 6;
    int i = blockIdx.x * SCAN_B + tid;
    int v = (i < n) ? kc[i] : 0;
#pragma unroll
    for (int d = 1; d < 64; d <<= 1) v += __shfl_xor(v, d, 64);
    if (lane == 0) wpart[w] = v;
    __syncthreads();
    if (tid < 16) {
        int t = wpart[tid];
#pragma unroll
        for (int d = 1; d < 16; d <<= 1) t += __shfl_xor(t, d, 64);
        if (tid == 0) bsum[blockIdx.x] = t;
    }
}

// S3: each block re-scans bsum in-register (nb<=64) for its base, then
// offs[i+1] = inclusive prefix, dinv[i] = 1/sqrt(1+kc[i]).
__global__ __launch_bounds__(SCAN_B) void k_scan3(const int* __restrict__ kc,
                                                  const int* __restrict__ bsum,
                                                  int* __restrict__ offs,
                                                  float* __restrict__ dinv,
                                                  int n, int nb) {
    __shared__ int wsum[16];
    __shared__ int sbase;
    int tid = threadIdx.x, lane = tid & 63, w = tid >> 6;
    if (tid < 64) {  // wave 0: exclusive prefix of bsum at blockIdx.x
        int v = (tid < nb) ? bsum[tid] : 0;
        int s = v;
#pragma unroll
        for (int d = 1; d < 64; d <<= 1) {
            int u = __shfl_up(s, d, 64);
            if (tid >= d) s += u;
        }
        if (tid == blockIdx.x) sbase = s - v;
    }
    int i = blockIdx.x * SCAN_B + tid;
    int v = (i < n) ? kc[i] : 0;
    int s = v;
#pragma unroll
    for (int d = 1; d < 64; d <<= 1) {
        int u = __shfl_up(s, d, 64);
        if (lane >= d) s += u;
    }
    if (lane == 63) wsum[w] = s;
    __syncthreads();
    if (tid < 16) {
        int t = wsum[tid];
#pragma unroll
        for (int d = 1; d < 16; d <<= 1) {
            int u = __shfl_up(t, d, 64);
            if (tid >= d) t += u;
        }
        wsum[tid] = t;
    }
    __syncthreads();
    int base = sbase + ((w == 0) ? 0 : wsum[w - 1]);
    if (i < n) {
        offs[i + 1] = base + s;
        dinv[i] = 1.0f / sqrtf(1.0f + (float)v);
        if (i == 0) offs[0] = 0;
    }
}

// Atomic-free fill: unique slot per edge (offs[dst] + rank).
__global__ void k_fill(const int* __restrict__ src, const int* __restrict__ dst,
                       const int* __restrict__ rank, const int* __restrict__ offs,
                       int* __restrict__ csr, int E) {
    int e = blockIdx.x * blockDim.x + threadIdx.x;
    if (e < E) csr[offs[dst[e]] + rank[e]] = src[e];
}

// tsA/tsB[64-tile] = fp16((x_tile[64x128] @ W[128x64]) * dinv), dims split
// 0..31 -> tsA, 32..63 -> tsB (32-dim 64B rows, 3.2MB each: per-XCD L2 fit).
__global__ __launch_bounds__(256) void k_mm1(const float* __restrict__ x,
                                             const float* __restrict__ W,
                                             const float* __restrict__ dinv,
                                             __half* __restrict__ tsA,
                                             __half* __restrict__ tsB, int n) {
    __shared__ float xs[64 * 68];
    __shared__ float ws[64 * 68];
    const int tid = threadIdx.x;
    const int m0 = blockIdx.x * 64;
    const int j = tid & 15;
    const int i = tid >> 4;

    const float4* x4 = (const float4*)x;
    const float4* W4 = (const float4*)W;

    float4 acc[4];
#pragma unroll
    for (int r = 0; r < 4; ++r) acc[r] = make_float4(0.f, 0.f, 0.f, 0.f);

    for (int kk = 0; kk < IN_DIM; kk += 64) {
        __syncthreads();
        for (int idx = tid; idx < 64 * 16; idx += 256) {
            int row = idx >> 4, c4 = idx & 15;
            float4 v = make_float4(0.f, 0.f, 0.f, 0.f);
            if (m0 + row < n) v = x4[(size_t)(m0 + row) * 32 + (kk >> 2) + c4];
            *(float4*)&xs[row * 68 + 4 * c4] = v;
            *(float4*)&ws[row * 68 + 4 * c4] = W4[(size_t)(kk + row) * 16 + c4];
        }
        __syncthreads();
#pragma unroll 1   // dynamic: bounds LDS-read hoisting / VGPR pressure (R5 lesson)
        for (int k4 = 0; k4 < 16; ++k4) {
            float4 a[4];
#pragma unroll
            for (int r = 0; r < 4; ++r)
                a[r] = *(const float4*)&xs[(4 * i + r) * 68 + 4 * k4];
#pragma unroll
            for (int kc = 0; kc < 4; ++kc) {
                float4 bv = *(const float4*)&ws[(4 * k4 + kc) * 68 + 4 * j];
#pragma unroll
                for (int r = 0; r < 4; ++r) {
                    float av = (&a[r].x)[kc];
                    acc[r].x = fmaf(av, bv.x, acc[r].x);
                    acc[r].y = fmaf(av, bv.y, acc[r].y);
                    acc[r].z = fmaf(av, bv.z, acc[r].z);
                    acc[r].w = fmaf(av, bv.w, acc[r].w);
                }
            }
        }
    }

#pragma unroll
    for (int r = 0; r < 4; ++r) {
        int row = m0 + 4 * i + r;
        if (row < n) {
            float di = dinv[row];
            float4 tv = acc[r];
            __half2 h0 = __floats2half2_rn(tv.x * di, tv.y * di);
            __half2 h1 = __floats2half2_rn(tv.z * di, tv.w * di);
            __half2* p = (j < 8)
                ? (__half2*)&tsA[(size_t)row * 32 + 4 * j]
                : (__half2*)&tsB[(size_t)row * 32 + 4 * (j - 8)];
            p[0] = h0;
            p[1] = h1;
        }
    }
}

// Split-half gather + layer-1 epilogue:
// hhX[i] = fp16(dinv * elu(dinv*(sum+self) + b1_half)).
// Wave = (node, half). half = (bid>>2)&1 so under bid%8 XCD round-robin,
// XCDs 0-3 touch only the A buffers, XCDs 4-7 only B (3.2MB per-XCD L2 fit).
// 16 groups x 4 lanes; 2 preloaded batches = 32 rows in flight; clamped
// slots alias last row's line. Tail loop deg>32 (P~1e-4). 4x shfl_xor.
__global__ __launch_bounds__(256) void k_gather_hh(const int* __restrict__ off,
                                                   const int* __restrict__ csr,
                                                   const float* __restrict__ dinv,
                                                   const __half* __restrict__ tsA,
                                                   const __half* __restrict__ tsB,
                                                   const float* __restrict__ b1,
                                                   __half* __restrict__ hhA,
                                                   __half* __restrict__ hhB, int n) {
    int bid = blockIdx.x;
    int half = (bid >> 2) & 1;
    int jb = (bid >> 3) * 4 + (bid & 3);
    int node = jb * 4 + (threadIdx.x >> 6);
    if (node >= n) return;
    const __half* T = half ? tsB : tsA;
    __half* H = half ? hhB : hhA;
    int lane = threadIdx.x & 63;
    int g = lane >> 2, sub = lane & 3;
    int s0 = off[node], s1 = off[node + 1];
    float acc[8];
#pragma unroll
    for (int q = 0; q < 8; ++q) acc[q] = 0.f;

    if (s1 > s0) {
        int last = s1 - 1;
        int p0 = s0 + g, p1 = p0 + 16;
        int i0 = csr[p0 < s1 ? p0 : last];
        int i1 = csr[p1 < s1 ? p1 : last];
        float4 r0 = *(const float4*)&T[(size_t)i0 * 32 + sub * 8];
        float4 r1 = *(const float4*)&T[(size_t)i1 * 32 + sub * 8];
        float m0 = (p0 < s1) ? 1.f : 0.f;
        float m1 = (p1 < s1) ? 1.f : 0.f;
        ACC8(r0, m0);
        ACC8(r1, m1);
        for (int k = s0 + 32 + g; k < s1; k += 16) {  // rare (deg>32)
            int iv = csr[k];
            float4 rv = *(const float4*)&T[(size_t)iv * 32 + sub * 8];
            ACC8(rv, 1.f);
        }
    }

#pragma unroll
    for (int q = 0; q < 8; ++q) {
        acc[q] += __shfl_xor(acc[q], 4, 64);
        acc[q] += __shfl_xor(acc[q], 8, 64);
        acc[q] += __shfl_xor(acc[q], 16, 64);
        acc[q] += __shfl_xor(acc[q], 32, 64);
    }

    if (g == 0) {  // lanes 0..3 hold sub-chunks of this half
        float4 sr = *(const float4*)&T[(size_t)node * 32 + sub * 8];
        const __half2* sh = (const __half2*)&sr;
        float di = dinv[node];
        const float4* b4 = (const float4*)b1;
        float4 ba = b4[half * 8 + sub * 2];
        float4 bb = b4[half * 8 + sub * 2 + 1];
        float2 f0 = __half22float2(sh[0]);
        float2 f1 = __half22float2(sh[1]);
        float2 f2 = __half22float2(sh[2]);
        float2 f3 = __half22float2(sh[3]);
        float e0 = elu1((acc[0] + f0.x) * di + ba.x) * di;
        float e1 = elu1((acc[1] + f0.y) * di + ba.y) * di;
        float e2 = elu1((acc[2] + f1.x) * di + ba.z) * di;
        float e3 = elu1((acc[3] + f1.y) * di + ba.w) * di;
        float e4 = elu1((acc[4] + f2.x) * di + bb.x) * di;
        float e5 = elu1((acc[5] + f2.y) * di + bb.y) * di;
        float e6 = elu1((acc[6] + f3.x) * di + bb.z) * di;
        float e7 = elu1((acc[7] + f3.y) * di + bb.w) * di;
        float4 outv;
        __half2* op = (__half2*)&outv;
        op[0] = __floats2half2_rn(e0, e1);
        op[1] = __floats2half2_rn(e2, e3);
        op[2] = __floats2half2_rn(e4, e5);
        op[3] = __floats2half2_rn(e6, e7);
        *(float4*)&H[(size_t)node * 32 + sub * 8] = outv;
    }
}

// Layer-2/3 SHARED split-half gather: g[i] = dinv[i]*(sum + hh[i]) (f32).
__global__ __launch_bounds__(256) void k_gather_g(const int* __restrict__ off,
                                                  const int* __restrict__ csr,
                                                  const float* __restrict__ dinv,
                                                  const __half* __restrict__ hhA,
                                                  const __half* __restrict__ hhB,
                                                  float* __restrict__ gout, int n) {
    int bid = blockIdx.x;
    int half = (bid >> 2) & 1;
    int jb = (bid >> 3) * 4 + (bid & 3);
    int node = jb * 4 + (threadIdx.x >> 6);
    if (node >= n) return;
    const __half* T = half ? hhB : hhA;
    int lane = threadIdx.x & 63;
    int g = lane >> 2, sub = lane & 3;
    int s0 = off[node], s1 = off[node + 1];
    float acc[8];
#pragma unroll
    for (int q = 0; q < 8; ++q) acc[q] = 0.f;

    if (s1 > s0) {
        int last = s1 - 1;
        int p0 = s0 + g, p1 = p0 + 16;
        int i0 = csr[p0 < s1 ? p0 : last];
        int i1 = csr[p1 < s1 ? p1 : last];
        float4 r0 = *(const float4*)&T[(size_t)i0 * 32 + sub * 8];
        float4 r1 = *(const float4*)&T[(size_t)i1 * 32 + sub * 8];
        float m0 = (p0 < s1) ? 1.f : 0.f;
        float m1 = (p1 < s1) ? 1.f : 0.f;
        ACC8(r0, m0);
        ACC8(r1, m1);
        for (int k = s0 + 32 + g; k < s1; k += 16) {  // rare (deg>32)
            int iv = csr[k];
            float4 rv = *(const float4*)&T[(size_t)iv * 32 + sub * 8];
            ACC8(rv, 1.f);
        }
    }

#pragma unroll
    for (int q = 0; q < 8; ++q) {
        acc[q] += __shfl_xor(acc[q], 4, 64);
        acc[q] += __shfl_xor(acc[q], 8, 64);
        acc[q] += __shfl_xor(acc[q], 16, 64);
        acc[q] += __shfl_xor(acc[q], 32, 64);
    }

    if (g == 0) {
        float4 sr = *(const float4*)&T[(size_t)node * 32 + sub * 8];
        const __half2* sh = (const __half2*)&sr;
        float di = dinv[node];
        float2 f0 = __half22float2(sh[0]);
        float2 f1 = __half22float2(sh[1]);
        float2 f2 = __half22float2(sh[2]);
        float2 f3 = __half22float2(sh[3]);
        float o0 = (acc[0] + f0.x) * di;
        float o1 = (acc[1] + f0.y) * di;
        float o2 = (acc[2] + f1.x) * di;
        float o3 = (acc[3] + f1.y) * di;
        float o4 = (acc[4] + f2.x) * di;
        float o5 = (acc[5] + f2.y) * di;
        float o6 = (acc[6] + f3.x) * di;
        float o7 = (acc[7] + f3.y) * di;
        float* gp = &gout[(size_t)node * 64 + half * 32 + sub * 8];
        *(float4*)gp = make_float4(o0, o1, o2, o3);
        *(float4*)(gp + 4) = make_float4(o4, o5, o6, o7);
    }
}

// mu|sig GEMM + bias + elu + pool stage-1.
// P[row][0..63] = elu(g@Wmu + bmu), P[row][64..127] = elu(g@Wsig + bsig),
// staged in LDS (reusing wc) then column-reduced per graph segment with
// boundary-flush atomics into sums (mu at [0,4096), sig at [4096,8192)).
__global__ __launch_bounds__(256) void k_mm_pool(const float* __restrict__ g,
                                                 const float* __restrict__ Wmu,
                                                 const float* __restrict__ Wsig,
                                                 const float* __restrict__ bmu,
                                                 const float* __restrict__ bsig,
                                                 const int* __restrict__ batch,
                                                 float* __restrict__ sums, int n) {
    __shared__ float hs[64 * 68];
    __shared__ float wc[64 * 132];  // [k][0..63]=Wmu, [k][64..127]=Wsig; later P
    __shared__ int bs[64];
    const int tid = threadIdx.x;
    const int m0 = blockIdx.x * 64;
    const int j = tid & 15;
    const int i = tid >> 4;

    const float4* g4 = (const float4*)g;
    const float4* Wm4 = (const float4*)Wmu;
    const float4* Ws4 = (const float4*)Wsig;
    for (int idx = tid; idx < 64 * 16; idx += 256) {
        int row = idx >> 4, c4 = idx & 15;
        float4 v = make_float4(0.f, 0.f, 0.f, 0.f);
        if (m0 + row < n) v = g4[(size_t)(m0 + row) * 16 + c4];
        *(float4*)&hs[row * 68 + 4 * c4] = v;
        *(float4*)&wc[row * 132 + 4 * c4] = Wm4[(size_t)row * 16 + c4];
        *(float4*)&wc[row * 132 + 64 + 4 * c4] = Ws4[(size_t)row * 16 + c4];
    }
    if (tid < 64) bs[tid] = (m0 + tid < n) ? batch[m0 + tid] : -1;
    __syncthreads();

    float4 accm[4], accs[4];
#pragma unroll
    for (int r = 0; r < 4; ++r) {
        accm[r] = make_float4(0.f, 0.f, 0.f, 0.f);
        accs[r] = make_float4(0.f, 0.f, 0.f, 0.f);
    }

#pragma unroll 1   // dynamic: bounds LDS-read hoisting / VGPR pressure (R5 lesson)
    for (int k4 = 0; k4 < 16; ++k4) {
        float4 a[4];
#pragma unroll
        for (int r = 0; r < 4; ++r)
            a[r] = *(const float4*)&hs[(4 * i + r) * 68 + 4 * k4];
#pragma unroll
        for (int kc = 0; kc < 4; ++kc) {
            float4 bm = *(const float4*)&wc[(4 * k4 + kc) * 132 + 4 * j];
            float4 bsv = *(const float4*)&wc[(4 * k4 + kc) * 132 + 64 + 4 * j];
#pragma unroll
            for (int r = 0; r < 4; ++r) {
                float av = (&a[r].x)[kc];
                accm[r].x = fmaf(av, bm.x, accm[r].x);
                accm[r].y = fmaf(av, bm.y, accm[r].y);
                accm[r].z = fmaf(av, bm.z, accm[r].z);
                accm[r].w = fmaf(av, bm.w, accm[r].w);
                accs[r].x = fmaf(av, bsv.x, accs[r].x);
                accs[r].y = fmaf(av, bsv.y, accs[r].y);
                accs[r].z = fmaf(av, bsv.z, accs[r].z);
                accs[r].w = fmaf(av, bsv.w, accs[r].w);
            }
        }
    }

    float4 bm = ((const float4*)bmu)[j];
    float4 bg = ((const float4*)bsig)[j];
    __syncthreads();  // all weight reads done before overwriting wc with P

#pragma unroll
    for (int r = 0; r < 4; ++r) {
        int row = 4 * i + r;
        float4 m = accm[r], s = accs[r];
        m.x = elu1(m.x + bm.x);
        m.y = elu1(m.y + bm.y);
        m.z = elu1(m.z + bm.z);
        m.w = elu1(m.w + bm.w);
        s.x = elu1(s.x + bg.x);
        s.y = elu1(s.y + bg.y);
        s.z = elu1(s.z + bg.z);
        s.w = elu1(s.w + bg.w);
        *(float4*)&wc[row * 132 + 4 * j] = m;
        *(float4*)&wc[row * 132 + 64 + 4 * j] = s;
    }
    __syncthreads();

    // Pool: thread (d, seg) reduces column d over rows [seg*32, seg*32+32),
    // flushing at graph boundaries (batch sorted).
    int d = tid & 127, seg = tid >> 7;
    int base = (d < 64) ? d : (64 * 64 - 64 + d);  // mu: g*64+d, sig: 4096+g*64+(d-64)
    float acc = 0.f;
    int gcur = -1;
    int r0 = seg * 32;
    for (int r = r0; r < r0 + 32; ++r) {
        int gb = bs[r];
        if (gb < 0) break;
        float v = wc[r * 132 + d];
        if (gb != gcur) {
            if (gcur >= 0) atomicAdd(&sums[base + gcur * 64], acc);
            acc = 0.f;
            gcur = gb;
        }
        acc += v;
    }
    if (gcur >= 0) atomicAdd(&sums[base + gcur * 64], acc);
}

// Pool stage 2: one thread per output element; cnt via binary search.
__global__ void k_pool_final(const float* __restrict__ sums,
                             const int* __restrict__ batch,
                             float* __restrict__ out, int n) {
    int i = blockIdx.x * blockDim.x + threadIdx.x;
    if (i >= 2 * N_GRAPHS * ZDIM) return;
    int g = (i >> 6) & 63;
    int lo = 0, hi = n;
    while (lo < hi) { int m = (lo + hi) >> 1; if (batch[m] < g) lo = m + 1; else hi = m; }
    int s = lo;
    lo = s; hi = n;
    while (lo < hi) { int m = (lo + hi) >> 1; if (batch[m] < g + 1) lo = m + 1; else hi = m; }
    float c = fmaxf((float)(lo - s), 1.0f);
    out[i] = sums[i] / c;
}

extern "C" void kernel_launch(void* const* d_in, const int* in_sizes, int n_in,
                              void* d_out, int out_size, void* d_ws, size_t ws_size,
                              hipStream_t stream) {
    const float* x    = (const float*)d_in[0];
    const int*   ei   = (const int*)d_in[1];
    const int*   batch= (const int*)d_in[2];
    // d_in[3] = num_graphs (scalar, known 64)
    const float* W1   = (const float*)d_in[4];
    const float* b1   = (const float*)d_in[5];
    const float* Wmu  = (const float*)d_in[6];
    const float* bmu  = (const float*)d_in[7];
    const float* Wsig = (const float*)d_in[8];
    const float* bsig = (const float*)d_in[9];
    float* out = (float*)d_out;

    const int n = in_sizes[0] / IN_DIM;   // 50000
    const int E = in_sizes[1] / 2;        // 800000
    const int* src = ei;
    const int* dst = ei + E;
    const int NSB = (n + SCAN_B - 1) / SCAN_B;  // scan blocks (49)

    float* ws = (float*)d_ws;
    size_t off_w = 0;
    int*   kc   = (int*)(ws + off_w); off_w += 50048;
    float* sums = ws + off_w; off_w += 8192;   // contiguous with kc: one memset
    float* dinv = ws + off_w; off_w += 50048;
    int*   offs = (int*)(ws + off_w); off_w += 50056;
    int*   bsum = (int*)(ws + off_w); off_w += 64;
    int*   rank = (int*)(ws + off_w); off_w += 800000;
    int*   csr  = (int*)(ws + off_w); off_w += 800000;
    off_w = (off_w + 15) & ~(size_t)15;
    const size_t HALF16 = (size_t)50048 * 16;  // n*32 halfs in float units
    __half* tsA = (__half*)(ws + off_w); off_w += HALF16;  // dims 0..31
    __half* tsB = (__half*)(ws + off_w); off_w += HALF16;  // dims 32..63
    __half* hhA = (__half*)(ws + off_w); off_w += HALF16;
    __half* hhB = (__half*)(ws + off_w); off_w += HALF16;
    float*  gbuf = ws + off_w; off_w += (size_t)50048 * 64; // f32 g = S*h

    const int gE  = (E + 255) / 256;
    const int NB  = (n + 63) / 64;    // 64-node GEMM tiles
    const int bph = (n + 3) / 4;      // gather blocks per half
    const int bph4 = (bph + 3) & ~3;  // multiple of 4 -> grid multiple of 8
    const int gG = 2 * bph4;          // split-half gather grid (25000)

    // CSR build + normalization (kc+sums zeroed in ONE contiguous memset)
    hipMemsetAsync(kc, 0, (50048 + 8192) * sizeof(int), stream);
    k_count<<<gE, 256, 0, stream>>>(dst, kc, rank, E);
    k_scan1<<<NSB, SCAN_B, 0, stream>>>(kc, bsum, n);
    k_scan3<<<NSB, SCAN_B, 0, stream>>>(kc, bsum, offs, dinv, n, NSB);
    k_fill<<<gE, 256, 0, stream>>>(src, dst, rank, offs, csr, E);

    // layer 1: tsA|tsB = fp16((x@W1)*dinv) split; hhA|hhB = fp16(dinv*elu(...))
    k_mm1<<<NB, 256, 0, stream>>>(x, W1, dinv, tsA, tsB, n);
    k_gather_hh<<<gG, 256, 0, stream>>>(offs, csr, dinv, tsA, tsB, b1, hhA, hhB, n);

    // layers 2/3 shared gather: g = S*h (f32)
    k_gather_g<<<gG, 256, 0, stream>>>(offs, csr, dinv, hhA, hhB, gbuf, n);

    // mu|sig GEMM + bias + elu + fused pool stage-1
    k_mm_pool<<<NB, 256, 0, stream>>>(gbuf, Wmu, Wsig, bmu, bsig, batch, sums, n);
    k_pool_final<<<(2 * N_GRAPHS * ZDIM + 255) / 256, 256, 0, stream>>>(sums, batch, out, n);
}

// Round 4
// 269.371 us; speedup vs baseline: 1.0125x; 1.0125x over previous
//
#include <hip/hip_runtime.h>
#include <hip/hip_fp16.h>

// GCN encoder: 3x GCNConv (+self-loops, sym deg^-1/2 norm) + ELU + mean-pool.
// N=50000, E=800000, IN=128, HID=64, ZDIM=64, G=64. f32 in/out.
// R7: CSR gather. R8: parallel scan. R9: fp16 gathered operands.
// R11: atomic-free fill. R12/13: fused pool. R15: 8 rows in flight -> 252.6.
// R16: algebraic restructure S(hW)=(Sh)W -> one shared 64-dim gather. 249.6.
// R17: MLP gather decomposition, 32 rows in flight/wave -> 238.1.
// R18: XCD-split gather FAILED (272.7). Counters: gather VALUBusy~105%,
//     hbm 7%, FETCH~ideal => gathers are VALU-ISSUE-bound on per-wave
//     overhead (reduction + 8xELU epilogue at 12.5% lane activity), not on
//     memory. Reverted split.
// R19: ISSUE-LEAN GATHER. 2 nodes/wave (4 row-groups x 8 chunk-lanes each),
//     6 preloaded batches = 24 slots (tail ~1.7% of nodes), 48 rows in
//     flight/wave. Reduction 2 shfl rounds (was 3). Epilogue distributed
//     across all 64 lanes (2 elems/lane, predicated const-index selects),
//     coalesced half2/float2 stores. ~3x fewer issues/node in both gathers.

#define IN_DIM 128
#define HID 64
#define ZDIM 64
#define N_GRAPHS 64
#define SCAN_B 1024

__device__ __forceinline__ float elu1(float x) {
    return x > 0.f ? x : expm1f(x);
}

// Accumulate 8 fp16 (held in a float4 raw register) with mask MV into acc[8].
#define ACC8(RV, MV) do { \
    const __half2* _hp = (const __half2*)&(RV); \
    float2 _f0 = __half22float2(_hp[0]); \
    float2 _f1 = __half22float2(_hp[1]); \
    float2 _f2 = __half22float2(_hp[2]); \
    float2 _f3 = __half22float2(_hp[3]); \
    acc[0] = fmaf((MV), _f0.x, acc[0]); \
    acc[1] = fmaf((MV), _f0.y, acc[1]); \
    acc[2] = fmaf((MV), _f1.x, acc[2]); \
    acc[3] = fmaf((MV), _f1.y, acc[3]); \
    acc[4] = fmaf((MV), _f2.x, acc[4]); \
    acc[5] = fmaf((MV), _f2.y, acc[5]); \
    acc[6] = fmaf((MV), _f3.x, acc[6]); \
    acc[7] = fmaf((MV), _f3.y, acc[7]); \
  } while (0)

// rank[e] = within-dst arrival index; kc[d] ends as deg(d).
__global__ void k_count(const int* __restrict__ dst, int* __restrict__ kc,
                        int* __restrict__ rank, int E) {
    int e = blockIdx.x * blockDim.x + threadIdx.x;
    if (e < E) rank[e] = atomicAdd(&kc[dst[e]], 1);
}

// S1: per-block sum of kc -> bsum[blk]
__global__ __launch_bounds__(SCAN_B) void k_scan1(const int* __restrict__ kc,
                                                  int* __restrict__ bsum, int n) {
    __shared__ int wpart[16];
    int tid = threadIdx.x, lane = tid & 63, w = tid >> 6;
    int i = blockIdx.x * SCAN_B + tid;
    int v = (i < n) ? kc[i] : 0;
#pragma unroll
    for (int d = 1; d < 64; d <<= 1) v += __shfl_xor(v, d, 64);
    if (lane == 0) wpart[w] = v;
    __syncthreads();
    if (tid < 16) {
        int t = wpart[tid];
#pragma unroll
        for (int d = 1; d < 16; d <<= 1) t += __shfl_xor(t, d, 64);
        if (tid == 0) bsum[blockIdx.x] = t;
    }
}

// S3: each block re-scans bsum in-register (nb<=64) for its base, then
// offs[i+1] = inclusive prefix, dinv[i] = 1/sqrt(1+kc[i]).
__global__ __launch_bounds__(SCAN_B) void k_scan3(const int* __restrict__ kc,
                                                  const int* __restrict__ bsum,
                                                  int* __restrict__ offs,
                                                  float* __restrict__ dinv,
                                                  int n, int nb) {
    __shared__ int wsum[16];
    __shared__ int sbase;
    int tid = threadIdx.x, lane = tid & 63, w = tid >> 6;
    if (tid < 64) {  // wave 0: exclusive prefix of bsum at blockIdx.x
        int v = (tid < nb) ? bsum[tid] : 0;
        int s = v;
#pragma unroll
        for (int d = 1; d < 64; d <<= 1) {
            int u = __shfl_up(s, d, 64);
            if (tid >= d) s += u;
        }
        if (tid == blockIdx.x) sbase = s - v;
    }
    int i = blockIdx.x * SCAN_B + tid;
    int v = (i < n) ? kc[i] : 0;
    int s = v;
#pragma unroll
    for (int d = 1; d < 64; d <<= 1) {
        int u = __shfl_up(s, d, 64);
        if (lane >= d) s += u;
    }
    if (lane == 63) wsum[w] = s;
    __syncthreads();
    if (tid < 16) {
        int t = wsum[tid];
#pragma unroll
        for (int d = 1; d < 16; d <<= 1) {
            int u = __shfl_up(t, d, 64);
            if (tid >= d) t += u;
        }
        wsum[tid] = t;
    }
    __syncthreads();
    int base = sbase + ((w == 0) ? 0 : wsum[w - 1]);
    if (i < n) {
        offs[i + 1] = base + s;
        dinv[i] = 1.0f / sqrtf(1.0f + (float)v);
        if (i == 0) offs[0] = 0;
    }
}

// Atomic-free fill: unique slot per edge (offs[dst] + rank).
__global__ void k_fill(const int* __restrict__ src, const int* __restrict__ dst,
                       const int* __restrict__ rank, const int* __restrict__ offs,
                       int* __restrict__ csr, int E) {
    int e = blockIdx.x * blockDim.x + threadIdx.x;
    if (e < E) csr[offs[dst[e]] + rank[e]] = src[e];
}

// ts1h[64-tile] = fp16((x_tile[64x128] @ W[128x64]) * dinv).
__global__ __launch_bounds__(256) void k_mm1(const float* __restrict__ x,
                                             const float* __restrict__ W,
                                             const float* __restrict__ dinv,
                                             __half* __restrict__ ts1h, int n) {
    __shared__ float xs[64 * 68];
    __shared__ float ws[64 * 68];
    const int tid = threadIdx.x;
    const int m0 = blockIdx.x * 64;
    const int j = tid & 15;
    const int i = tid >> 4;

    const float4* x4 = (const float4*)x;
    const float4* W4 = (const float4*)W;

    float4 acc[4];
#pragma unroll
    for (int r = 0; r < 4; ++r) acc[r] = make_float4(0.f, 0.f, 0.f, 0.f);

    for (int kk = 0; kk < IN_DIM; kk += 64) {
        __syncthreads();
        for (int idx = tid; idx < 64 * 16; idx += 256) {
            int row = idx >> 4, c4 = idx & 15;
            float4 v = make_float4(0.f, 0.f, 0.f, 0.f);
            if (m0 + row < n) v = x4[(size_t)(m0 + row) * 32 + (kk >> 2) + c4];
            *(float4*)&xs[row * 68 + 4 * c4] = v;
            *(float4*)&ws[row * 68 + 4 * c4] = W4[(size_t)(kk + row) * 16 + c4];
        }
        __syncthreads();
#pragma unroll 1   // dynamic: bounds LDS-read hoisting / VGPR pressure (R5 lesson)
        for (int k4 = 0; k4 < 16; ++k4) {
            float4 a[4];
#pragma unroll
            for (int r = 0; r < 4; ++r)
                a[r] = *(const float4*)&xs[(4 * i + r) * 68 + 4 * k4];
#pragma unroll
            for (int kc = 0; kc < 4; ++kc) {
                float4 bv = *(const float4*)&ws[(4 * k4 + kc) * 68 + 4 * j];
#pragma unroll
                for (int r = 0; r < 4; ++r) {
                    float av = (&a[r].x)[kc];
                    acc[r].x = fmaf(av, bv.x, acc[r].x);
                    acc[r].y = fmaf(av, bv.y, acc[r].y);
                    acc[r].z = fmaf(av, bv.z, acc[r].z);
                    acc[r].w = fmaf(av, bv.w, acc[r].w);
                }
            }
        }
    }

#pragma unroll
    for (int r = 0; r < 4; ++r) {
        int row = m0 + 4 * i + r;
        if (row < n) {
            float di = dinv[row];
            float4 tv = acc[r];
            __half2* p = (__half2*)&ts1h[(size_t)row * HID + 4 * j];
            p[0] = __floats2half2_rn(tv.x * di, tv.y * di);
            p[1] = __floats2half2_rn(tv.z * di, tv.w * di);
        }
    }
}

// Issue-lean gather + layer-1 epilogue:
// hh[i] = fp16(dinv * elu(dinv*(sum+self) + b1)).
// 2 nodes/wave: node = bid*8 + (tid>>5); 32 lanes/node = 4 row-groups (g)
// x 8 chunk-lanes (sub, 16B each). 6 preloaded batches cover slots
// s0..s0+23 (48 rows in flight/wave); tail loop for deg>24 (~1.7%).
// Reduction: 2 shfl_xor rounds (8,16) within the node's 32 lanes.
// Epilogue: ALL lanes active, 2 elems/lane (e0 = sub*8+2g), const-index
// predicated selects (no scratch), coalesced half2 store.
__global__ __launch_bounds__(256) void k_gather_hh(const int* __restrict__ off,
                                                   const int* __restrict__ csr,
                                                   const float* __restrict__ dinv,
                                                   const __half* __restrict__ ts,
                                                   const float* __restrict__ b1,
                                                   __half* __restrict__ hh, int n) {
    int node = blockIdx.x * 8 + (threadIdx.x >> 5);
    if (node >= n) return;
    int l32 = threadIdx.x & 31;
    int g = l32 >> 3, sub = l32 & 7;
    int s0 = off[node], s1 = off[node + 1];
    float acc[8];
#pragma unroll
    for (int q = 0; q < 8; ++q) acc[q] = 0.f;

    if (s1 > s0) {
        int last = s1 - 1;
        int idx[6];
        float m[6];
#pragma unroll
        for (int t = 0; t < 6; ++t) {
            int p = s0 + g + 4 * t;
            idx[t] = csr[p < s1 ? p : last];
            m[t] = (p < s1) ? 1.f : 0.f;
        }
        float4 r[6];
#pragma unroll
        for (int t = 0; t < 6; ++t)
            r[t] = *(const float4*)&ts[(size_t)idx[t] * 64 + sub * 8];
#pragma unroll
        for (int t = 0; t < 6; ++t) ACC8(r[t], m[t]);
        for (int k = s0 + 24 + g; k < s1; k += 4) {  // rare (deg>24)
            int iv = csr[k];
            float4 rv = *(const float4*)&ts[(size_t)iv * 64 + sub * 8];
            ACC8(rv, 1.f);
        }
    }

#pragma unroll
    for (int q = 0; q < 8; ++q) {
        acc[q] += __shfl_xor(acc[q], 8, 64);
        acc[q] += __shfl_xor(acc[q], 16, 64);
    }

    // Distributed epilogue: lane (g,sub) owns elements e0 = sub*8+2g, e0+1.
    float v0 = acc[0], v1 = acc[1];
    if (g == 1) { v0 = acc[2]; v1 = acc[3]; }
    if (g == 2) { v0 = acc[4]; v1 = acc[5]; }
    if (g == 3) { v0 = acc[6]; v1 = acc[7]; }
    int e0 = sub * 8 + 2 * g;
    float2 sf = __half22float2(*(const __half2*)&ts[(size_t)node * 64 + e0]);
    float di = dinv[node];
    float2 bv = *(const float2*)&b1[e0];
    float a0 = (v0 + sf.x) * di + bv.x;
    float a1 = (v1 + sf.y) * di + bv.y;
    *(__half2*)&hh[(size_t)node * 64 + e0] =
        __floats2half2_rn(elu1(a0) * di, elu1(a1) * di);
}

// Layer-2/3 SHARED gather: g[i] = dinv[i]*(sum + hh[i]) (f32).
// Same issue-lean structure; epilogue has no ELU (2 fma + float2 store).
__global__ __launch_bounds__(256) void k_gather_g(const int* __restrict__ off,
                                                  const int* __restrict__ csr,
                                                  const float* __restrict__ dinv,
                                                  const __half* __restrict__ hh,
                                                  float* __restrict__ gout, int n) {
    int node = blockIdx.x * 8 + (threadIdx.x >> 5);
    if (node >= n) return;
    int l32 = threadIdx.x & 31;
    int g = l32 >> 3, sub = l32 & 7;
    int s0 = off[node], s1 = off[node + 1];
    float acc[8];
#pragma unroll
    for (int q = 0; q < 8; ++q) acc[q] = 0.f;

    if (s1 > s0) {
        int last = s1 - 1;
        int idx[6];
        float m[6];
#pragma unroll
        for (int t = 0; t < 6; ++t) {
            int p = s0 + g + 4 * t;
            idx[t] = csr[p < s1 ? p : last];
            m[t] = (p < s1) ? 1.f : 0.f;
        }
        float4 r[6];
#pragma unroll
        for (int t = 0; t < 6; ++t)
            r[t] = *(const float4*)&hh[(size_t)idx[t] * 64 + sub * 8];
#pragma unroll
        for (int t = 0; t < 6; ++t) ACC8(r[t], m[t]);
        for (int k = s0 + 24 + g; k < s1; k += 4) {  // rare (deg>24)
            int iv = csr[k];
            float4 rv = *(const float4*)&hh[(size_t)iv * 64 + sub * 8];
            ACC8(rv, 1.f);
        }
    }

#pragma unroll
    for (int q = 0; q < 8; ++q) {
        acc[q] += __shfl_xor(acc[q], 8, 64);
        acc[q] += __shfl_xor(acc[q], 16, 64);
    }

    float v0 = acc[0], v1 = acc[1];
    if (g == 1) { v0 = acc[2]; v1 = acc[3]; }
    if (g == 2) { v0 = acc[4]; v1 = acc[5]; }
    if (g == 3) { v0 = acc[6]; v1 = acc[7]; }
    int e0 = sub * 8 + 2 * g;
    float2 sf = __half22float2(*(const __half2*)&hh[(size_t)node * 64 + e0]);
    float di = dinv[node];
    *(float2*)&gout[(size_t)node * 64 + e0] =
        make_float2((v0 + sf.x) * di, (v1 + sf.y) * di);
}

// mu|sig GEMM + bias + elu + pool stage-1.
// P[row][0..63] = elu(g@Wmu + bmu), P[row][64..127] = elu(g@Wsig + bsig),
// staged in LDS (reusing wc) then column-reduced per graph segment with
// boundary-flush atomics into sums (mu at [0,4096), sig at [4096,8192)).
__global__ __launch_bounds__(256) void k_mm_pool(const float* __restrict__ g,
                                                 const float* __restrict__ Wmu,
                                                 const float* __restrict__ Wsig,
                                                 const float* __restrict__ bmu,
                                                 const float* __restrict__ bsig,
                                                 const int* __restrict__ batch,
                                                 float* __restrict__ sums, int n) {
    __shared__ float hs[64 * 68];
    __shared__ float wc[64 * 132];  // [k][0..63]=Wmu, [k][64..127]=Wsig; later P
    __shared__ int bs[64];
    const int tid = threadIdx.x;
    const int m0 = blockIdx.x * 64;
    const int j = tid & 15;
    const int i = tid >> 4;

    const float4* g4 = (const float4*)g;
    const float4* Wm4 = (const float4*)Wmu;
    const float4* Ws4 = (const float4*)Wsig;
    for (int idx = tid; idx < 64 * 16; idx += 256) {
        int row = idx >> 4, c4 = idx & 15;
        float4 v = make_float4(0.f, 0.f, 0.f, 0.f);
        if (m0 + row < n) v = g4[(size_t)(m0 + row) * 16 + c4];
        *(float4*)&hs[row * 68 + 4 * c4] = v;
        *(float4*)&wc[row * 132 + 4 * c4] = Wm4[(size_t)row * 16 + c4];
        *(float4*)&wc[row * 132 + 64 + 4 * c4] = Ws4[(size_t)row * 16 + c4];
    }
    if (tid < 64) bs[tid] = (m0 + tid < n) ? batch[m0 + tid] : -1;
    __syncthreads();

    float4 accm[4], accs[4];
#pragma unroll
    for (int r = 0; r < 4; ++r) {
        accm[r] = make_float4(0.f, 0.f, 0.f, 0.f);
        accs[r] = make_float4(0.f, 0.f, 0.f, 0.f);
    }

#pragma unroll 1   // dynamic: bounds LDS-read hoisting / VGPR pressure (R5 lesson)
    for (int k4 = 0; k4 < 16; ++k4) {
        float4 a[4];
#pragma unroll
        for (int r = 0; r < 4; ++r)
            a[r] = *(const float4*)&hs[(4 * i + r) * 68 + 4 * k4];
#pragma unroll
        for (int kc = 0; kc < 4; ++kc) {
            float4 bm = *(const float4*)&wc[(4 * k4 + kc) * 132 + 4 * j];
            float4 bsv = *(const float4*)&wc[(4 * k4 + kc) * 132 + 64 + 4 * j];
#pragma unroll
            for (int r = 0; r < 4; ++r) {
                float av = (&a[r].x)[kc];
                accm[r].x = fmaf(av, bm.x, accm[r].x);
                accm[r].y = fmaf(av, bm.y, accm[r].y);
                accm[r].z = fmaf(av, bm.z, accm[r].z);
                accm[r].w = fmaf(av, bm.w, accm[r].w);
                accs[r].x = fmaf(av, bsv.x, accs[r].x);
                accs[r].y = fmaf(av, bsv.y, accs[r].y);
                accs[r].z = fmaf(av, bsv.z, accs[r].z);
                accs[r].w = fmaf(av, bsv.w, accs[r].w);
            }
        }
    }

    float4 bm = ((const float4*)bmu)[j];
    float4 bg = ((const float4*)bsig)[j];
    __syncthreads();  // all weight reads done before overwriting wc with P

#pragma unroll
    for (int r = 0; r < 4; ++r) {
        int row = 4 * i + r;
        float4 m = accm[r], s = accs[r];
        m.x = elu1(m.x + bm.x);
        m.y = elu1(m.y + bm.y);
        m.z = elu1(m.z + bm.z);
        m.w = elu1(m.w + bm.w);
        s.x = elu1(s.x + bg.x);
        s.y = elu1(s.y + bg.y);
        s.z = elu1(s.z + bg.z);
        s.w = elu1(s.w + bg.w);
        *(float4*)&wc[row * 132 + 4 * j] = m;
        *(float4*)&wc[row * 132 + 64 + 4 * j] = s;
    }
    __syncthreads();

    // Pool: thread (d, seg) reduces column d over rows [seg*32, seg*32+32),
    // flushing at graph boundaries (batch sorted).
    int d = tid & 127, seg = tid >> 7;
    int base = (d < 64) ? d : (64 * 64 - 64 + d);  // mu: g*64+d, sig: 4096+g*64+(d-64)
    float acc = 0.f;
    int gcur = -1;
    int r0 = seg * 32;
    for (int r = r0; r < r0 + 32; ++r) {
        int gb = bs[r];
        if (gb < 0) break;
        float v = wc[r * 132 + d];
        if (gb != gcur) {
            if (gcur >= 0) atomicAdd(&sums[base + gcur * 64], acc);
            acc = 0.f;
            gcur = gb;
        }
        acc += v;
    }
    if (gcur >= 0) atomicAdd(&sums[base + gcur * 64], acc);
}

// Pool stage 2: one thread per output element; cnt via binary search.
__global__ void k_pool_final(const float* __restrict__ sums,
                             const int* __restrict__ batch,
                             float* __restrict__ out, int n) {
    int i = blockIdx.x * blockDim.x + threadIdx.x;
    if (i >= 2 * N_GRAPHS * ZDIM) return;
    int g = (i >> 6) & 63;
    int lo = 0, hi = n;
    while (lo < hi) { int m = (lo + hi) >> 1; if (batch[m] < g) lo = m + 1; else hi = m; }
    int s = lo;
    lo = s; hi = n;
    while (lo < hi) { int m = (lo + hi) >> 1; if (batch[m] < g + 1) lo = m + 1; else hi = m; }
    float c = fmaxf((float)(lo - s), 1.0f);
    out[i] = sums[i] / c;
}

extern "C" void kernel_launch(void* const* d_in, const int* in_sizes, int n_in,
                              void* d_out, int out_size, void* d_ws, size_t ws_size,
                              hipStream_t stream) {
    const float* x    = (const float*)d_in[0];
    const int*   ei   = (const int*)d_in[1];
    const int*   batch= (const int*)d_in[2];
    // d_in[3] = num_graphs (scalar, known 64)
    const float* W1   = (const float*)d_in[4];
    const float* b1   = (const float*)d_in[5];
    const float* Wmu  = (const float*)d_in[6];
    const float* bmu  = (const float*)d_in[7];
    const float* Wsig = (const float*)d_in[8];
    const float* bsig = (const float*)d_in[9];
    float* out = (float*)d_out;

    const int n = in_sizes[0] / IN_DIM;   // 50000
    const int E = in_sizes[1] / 2;        // 800000
    const int* src = ei;
    const int* dst = ei + E;
    const int NSB = (n + SCAN_B - 1) / SCAN_B;  // scan blocks (49)

    float* ws = (float*)d_ws;
    size_t off_w = 0;
    int*   kc   = (int*)(ws + off_w); off_w += 50048;
    float* sums = ws + off_w; off_w += 8192;   // contiguous with kc: one memset
    float* dinv = ws + off_w; off_w += 50048;
    int*   offs = (int*)(ws + off_w); off_w += 50056;
    int*   bsum = (int*)(ws + off_w); off_w += 64;
    int*   rank = (int*)(ws + off_w); off_w += 800000;
    int*   csr  = (int*)(ws + off_w); off_w += 800000;
    off_w = (off_w + 15) & ~(size_t)15;
    const size_t BIG = (size_t)n * 64;
    __half* ts1h = (__half*)(ws + off_w); off_w += BIG / 2;  // fp16 (x@W1)*dinv
    __half* hh   = (__half*)(ws + off_w); off_w += BIG / 2;  // fp16 dinv*elu(layer1)
    float*  gbuf = ws + off_w; off_w += BIG;                 // f32 g = S*h

    const int gE  = (E + 255) / 256;
    const int gNW = (n + 7) / 8;      // 8 nodes per 256-thread block (2/wave)
    const int NB  = (n + 63) / 64;    // 64-node GEMM tiles

    // CSR build + normalization (kc+sums zeroed in ONE contiguous memset)
    hipMemsetAsync(kc, 0, (50048 + 8192) * sizeof(int), stream);
    k_count<<<gE, 256, 0, stream>>>(dst, kc, rank, E);
    k_scan1<<<NSB, SCAN_B, 0, stream>>>(kc, bsum, n);
    k_scan3<<<NSB, SCAN_B, 0, stream>>>(kc, bsum, offs, dinv, n, NSB);
    k_fill<<<gE, 256, 0, stream>>>(src, dst, rank, offs, csr, E);

    // layer 1: ts1h = fp16((x@W1)*dinv); hh = fp16(dinv*elu(S(xW1)+b1))
    k_mm1<<<NB, 256, 0, stream>>>(x, W1, dinv, ts1h, n);
    k_gather_hh<<<gNW, 256, 0, stream>>>(offs, csr, dinv, ts1h, b1, hh, n);

    // layers 2/3 shared gather: g = S*h (f32)
    k_gather_g<<<gNW, 256, 0, stream>>>(offs, csr, dinv, hh, gbuf, n);

    // mu|sig GEMM + bias + elu + fused pool stage-1
    k_mm_pool<<<NB, 256, 0, stream>>>(gbuf, Wmu, Wsig, bmu, bsig, batch, sums, n);
    k_pool_final<<<(2 * N_GRAPHS * ZDIM + 255) / 256, 256, 0, stream>>>(sums, batch, out, n);
}

// Round 5
// 220.203 us; speedup vs baseline: 1.2386x; 1.2233x over previous
//
#include <hip/hip_runtime.h>
#include <hip/hip_fp16.h>

// GCN encoder: 3x GCNConv (+self-loops, sym deg^-1/2 norm) + ELU + mean-pool.
// N=50000, E=800000, IN=128, HID=64, ZDIM=64, G=64. f32 in/out.
// R7: CSR gather. R8: parallel scan. R9: fp16 gathered operands.
// R11: atomic-free fill. R12/13: fused pool. R15: 8 rows in flight -> 252.6.
// R16: algebraic restructure S(hW)=(Sh)W -> one shared 64-dim gather. 249.6.
// R17: MLP gather decomposition, 32 rows in flight/wave -> 238.1. BEST.
// R18: XCD-split gather FAILED (272.7). R19: issue-lean gather FAILED
//     (269.4). Lesson: R17's gather shape (1 node/wave, 8x8, 4 clamped
//     batches) beats both restructures; static issue-count models of the
//     gather don't predict. Gathers reverted to R17 verbatim; frozen.
// R20: MFMA GEMMs. k_mm1/k_mm_pool cores -> mfma_f32_16x16x32_f16
//     (f16 in, f32 accum). Weights pre-swizzled once into fragment order
//     (k_wfrag, 16KB) so B-frag = one 16B load. A-frag: 8 consecutive
//     f32 -> f16 casts. Same k-mapping on A and B => permutation-invariant
//     in k; C/D mapping is the HW-verified col=lane&15,row=(lane>>4)*4+r.
//     mm_pool keeps the LDS column-reduce pool (P staged via LDS).

#define IN_DIM 128
#define HID 64
#define ZDIM 64
#define N_GRAPHS 64
#define SCAN_B 1024

typedef _Float16 half8 __attribute__((ext_vector_type(8)));
typedef float f32x4 __attribute__((ext_vector_type(4)));

__device__ __forceinline__ float elu1(float x) {
    return x > 0.f ? x : expm1f(x);
}

// Accumulate 8 fp16 (held in a float4 raw register) with mask MV into acc[8].
#define ACC8(RV, MV) do { \
    const __half2* _hp = (const __half2*)&(RV); \
    float2 _f0 = __half22float2(_hp[0]); \
    float2 _f1 = __half22float2(_hp[1]); \
    float2 _f2 = __half22float2(_hp[2]); \
    float2 _f3 = __half22float2(_hp[3]); \
    acc[0] = fmaf((MV), _f0.x, acc[0]); \
    acc[1] = fmaf((MV), _f0.y, acc[1]); \
    acc[2] = fmaf((MV), _f1.x, acc[2]); \
    acc[3] = fmaf((MV), _f1.y, acc[3]); \
    acc[4] = fmaf((MV), _f2.x, acc[4]); \
    acc[5] = fmaf((MV), _f2.y, acc[5]); \
    acc[6] = fmaf((MV), _f3.x, acc[6]); \
    acc[7] = fmaf((MV), _f3.y, acc[7]); \
  } while (0)

// rank[e] = within-dst arrival index; kc[d] ends as deg(d).
__global__ void k_count(const int* __restrict__ dst, int* __restrict__ kc,
                        int* __restrict__ rank, int E) {
    int e = blockIdx.x * blockDim.x + threadIdx.x;
    if (e < E) rank[e] = atomicAdd(&kc[dst[e]], 1);
}

// S1: per-block sum of kc -> bsum[blk]
__global__ __launch_bounds__(SCAN_B) void k_scan1(const int* __restrict__ kc,
                                                  int* __restrict__ bsum, int n) {
    __shared__ int wpart[16];
    int tid = threadIdx.x, lane = tid & 63, w = tid >> 6;
    int i = blockIdx.x * SCAN_B + tid;
    int v = (i < n) ? kc[i] : 0;
#pragma unroll
    for (int d = 1; d < 64; d <<= 1) v += __shfl_xor(v, d, 64);
    if (lane == 0) wpart[w] = v;
    __syncthreads();
    if (tid < 16) {
        int t = wpart[tid];
#pragma unroll
        for (int d = 1; d < 16; d <<= 1) t += __shfl_xor(t, d, 64);
        if (tid == 0) bsum[blockIdx.x] = t;
    }
}

// S3: each block re-scans bsum in-register (nb<=64) for its base, then
// offs[i+1] = inclusive prefix, dinv[i] = 1/sqrt(1+kc[i]).
__global__ __launch_bounds__(SCAN_B) void k_scan3(const int* __restrict__ kc,
                                                  const int* __restrict__ bsum,
                                                  int* __restrict__ offs,
                                                  float* __restrict__ dinv,
                                                  int n, int nb) {
    __shared__ int wsum[16];
    __shared__ int sbase;
    int tid = threadIdx.x, lane = tid & 63, w = tid >> 6;
    if (tid < 64) {  // wave 0: exclusive prefix of bsum at blockIdx.x
        int v = (tid < nb) ? bsum[tid] : 0;
        int s = v;
#pragma unroll
        for (int d = 1; d < 64; d <<= 1) {
            int u = __shfl_up(s, d, 64);
            if (tid >= d) s += u;
        }
        if (tid == blockIdx.x) sbase = s - v;
    }
    int i = blockIdx.x * SCAN_B + tid;
    int v = (i < n) ? kc[i] : 0;
    int s = v;
#pragma unroll
    for (int d = 1; d < 64; d <<= 1) {
        int u = __shfl_up(s, d, 64);
        if (lane >= d) s += u;
    }
    if (lane == 63) wsum[w] = s;
    __syncthreads();
    if (tid < 16) {
        int t = wsum[tid];
#pragma unroll
        for (int d = 1; d < 16; d <<= 1) {
            int u = __shfl_up(t, d, 64);
            if (tid >= d) t += u;
        }
        wsum[tid] = t;
    }
    __syncthreads();
    int base = sbase + ((w == 0) ? 0 : wsum[w - 1]);
    if (i < n) {
        offs[i + 1] = base + s;
        dinv[i] = 1.0f / sqrtf(1.0f + (float)v);
        if (i == 0) offs[0] = 0;
    }
}

// Atomic-free fill: unique slot per edge (offs[dst] + rank).
__global__ void k_fill(const int* __restrict__ src, const int* __restrict__ dst,
                       const int* __restrict__ rank, const int* __restrict__ offs,
                       int* __restrict__ csr, int E) {
    int e = blockIdx.x * blockDim.x + threadIdx.x;
    if (e < E) csr[offs[dst[e]] + rank[e]] = src[e];
}

// One-shot weight swizzle into MFMA fragment order.
// F1  [4ks][4ct][64l][8j]  = f16(W1 [(ks*32+(l>>4)*8+j)*64 + ct*16+(l&15)])
// Fmu [2ks][4ct][64l][8j]  = f16(Wmu[(ks*32+(l>>4)*8+j)*64 + ct*16+(l&15)])
// Fsig likewise. Same k-mapping as the A-side loads (permutation-invariant).
__global__ void k_wfrag(const float* __restrict__ W1,
                        const float* __restrict__ Wmu,
                        const float* __restrict__ Wsig,
                        __half* __restrict__ F1,
                        __half* __restrict__ Fmu,
                        __half* __restrict__ Fsig) {
    int e = blockIdx.x * 256 + threadIdx.x;
    if (e < 8192) {
        int j = e & 7, l = (e >> 3) & 63, ct = (e >> 9) & 3, ks = e >> 11;
        F1[e] = __float2half(W1[(ks * 32 + ((l >> 4) & 3) * 8 + j) * 64 + ct * 16 + (l & 15)]);
    }
    if (e < 4096) {
        int j = e & 7, l = (e >> 3) & 63, ct = (e >> 9) & 3, ks = e >> 11;
        int widx = (ks * 32 + ((l >> 4) & 3) * 8 + j) * 64 + ct * 16 + (l & 15);
        Fmu[e] = __float2half(Wmu[widx]);
        Fsig[e] = __float2half(Wsig[widx]);
    }
}

// ts1h = fp16((x @ W1) * dinv) via MFMA. Wave = 16 rows; 4 ct-tiles x 4 ks.
__global__ __launch_bounds__(256) void k_mm1(const float* __restrict__ x,
                                             const __half* __restrict__ F1,
                                             const float* __restrict__ dinv,
                                             __half* __restrict__ ts1h, int n) {
    int l = threadIdx.x & 63;
    int wave = threadIdx.x >> 6;
    int m0 = blockIdx.x * 64 + wave * 16;
    int row_a = m0 + (l & 15);
    if (row_a >= n) row_a = n - 1;  // clamp loads; stores guarded
    int kg = l >> 4;

    f32x4 acc0 = {0.f, 0.f, 0.f, 0.f};
    f32x4 acc1 = acc0, acc2 = acc0, acc3 = acc0;

    const float* xr = x + (size_t)row_a * IN_DIM + kg * 8;
#pragma unroll
    for (int ks = 0; ks < 4; ++ks) {
        float4 xa = *(const float4*)(xr + ks * 32);
        float4 xb = *(const float4*)(xr + ks * 32 + 4);
        half8 a;
        a[0] = (_Float16)xa.x; a[1] = (_Float16)xa.y;
        a[2] = (_Float16)xa.z; a[3] = (_Float16)xa.w;
        a[4] = (_Float16)xb.x; a[5] = (_Float16)xb.y;
        a[6] = (_Float16)xb.z; a[7] = (_Float16)xb.w;
        const __half* fb = F1 + ((size_t)(ks * 4) * 64 + l) * 8;
        half8 b0 = *(const half8*)(fb);
        half8 b1 = *(const half8*)(fb + 512);
        half8 b2 = *(const half8*)(fb + 1024);
        half8 b3 = *(const half8*)(fb + 1536);
        acc0 = __builtin_amdgcn_mfma_f32_16x16x32_f16(a, b0, acc0, 0, 0, 0);
        acc1 = __builtin_amdgcn_mfma_f32_16x16x32_f16(a, b1, acc1, 0, 0, 0);
        acc2 = __builtin_amdgcn_mfma_f32_16x16x32_f16(a, b2, acc2, 0, 0, 0);
        acc3 = __builtin_amdgcn_mfma_f32_16x16x32_f16(a, b3, acc3, 0, 0, 0);
    }
    int col = l & 15;
#pragma unroll
    for (int r = 0; r < 4; ++r) {
        int row = m0 + kg * 4 + r;  // C/D: row=(lane>>4)*4+reg, col=lane&15
        if (row < n) {
            float di = dinv[row];
            __half* p = &ts1h[(size_t)row * 64 + col];
            p[0]  = __float2half(acc0[r] * di);
            p[16] = __float2half(acc1[r] * di);
            p[32] = __float2half(acc2[r] * di);
            p[48] = __float2half(acc3[r] * di);
        }
    }
}

// R17 gather (frozen): hh[i] = fp16(dinv * elu(dinv*(sum+self) + b1)).
// Wave = node. group g=lane>>3 owns a row, chunk sub=lane&7 owns 16B of it.
// 4 preloaded batches = 32 rows in flight; clamped slots alias last row's
// line (L1 hit). Tail loop for deg>32 (P~1e-4). 3x shfl_xor group combine.
__global__ __launch_bounds__(256) void k_gather_hh(const int* __restrict__ off,
                                                   const int* __restrict__ csr,
                                                   const float* __restrict__ dinv,
                                                   const __half* __restrict__ ts,
                                                   const float* __restrict__ b1,
                                                   __half* __restrict__ hh, int n) {
    int node = blockIdx.x * 4 + (threadIdx.x >> 6);
    if (node >= n) return;
    int lane = threadIdx.x & 63;
    int g = lane >> 3, sub = lane & 7;
    int s0 = off[node], s1 = off[node + 1];
    float acc[8];
#pragma unroll
    for (int j = 0; j < 8; ++j) acc[j] = 0.f;

    if (s1 > s0) {
        int last = s1 - 1;
        int p0 = s0 + g, p1 = p0 + 8, p2 = p0 + 16, p3 = p0 + 24;
        int i0 = csr[p0 < s1 ? p0 : last];
        int i1 = csr[p1 < s1 ? p1 : last];
        int i2 = csr[p2 < s1 ? p2 : last];
        int i3 = csr[p3 < s1 ? p3 : last];
        float4 r0 = *(const float4*)&ts[(size_t)i0 * 64 + sub * 8];
        float4 r1 = *(const float4*)&ts[(size_t)i1 * 64 + sub * 8];
        float4 r2 = *(const float4*)&ts[(size_t)i2 * 64 + sub * 8];
        float4 r3 = *(const float4*)&ts[(size_t)i3 * 64 + sub * 8];
        float m0 = (p0 < s1) ? 1.f : 0.f;
        float m1 = (p1 < s1) ? 1.f : 0.f;
        float m2 = (p2 < s1) ? 1.f : 0.f;
        float m3 = (p3 < s1) ? 1.f : 0.f;
        ACC8(r0, m0);
        ACC8(r1, m1);
        ACC8(r2, m2);
        ACC8(r3, m3);
        for (int k = s0 + 32 + g; k < s1; k += 8) {  // rare (deg>32)
            int iv = csr[k];
            float4 rv = *(const float4*)&ts[(size_t)iv * 64 + sub * 8];
            ACC8(rv, 1.f);
        }
    }

#pragma unroll
    for (int j = 0; j < 8; ++j) {
        acc[j] += __shfl_xor(acc[j], 8, 64);
        acc[j] += __shfl_xor(acc[j], 16, 64);
        acc[j] += __shfl_xor(acc[j], 32, 64);
    }

    if (g == 0) {
        float4 sr = *(const float4*)&ts[(size_t)node * 64 + sub * 8];
        const __half2* sh = (const __half2*)&sr;
        float di = dinv[node];
        const float4* b4 = (const float4*)b1;
        float4 ba = b4[sub * 2], bb = b4[sub * 2 + 1];
        float2 f0 = __half22float2(sh[0]);
        float2 f1 = __half22float2(sh[1]);
        float2 f2 = __half22float2(sh[2]);
        float2 f3 = __half22float2(sh[3]);
        float e0 = elu1((acc[0] + f0.x) * di + ba.x) * di;
        float e1 = elu1((acc[1] + f0.y) * di + ba.y) * di;
        float e2 = elu1((acc[2] + f1.x) * di + ba.z) * di;
        float e3 = elu1((acc[3] + f1.y) * di + ba.w) * di;
        float e4 = elu1((acc[4] + f2.x) * di + bb.x) * di;
        float e5 = elu1((acc[5] + f2.y) * di + bb.y) * di;
        float e6 = elu1((acc[6] + f3.x) * di + bb.z) * di;
        float e7 = elu1((acc[7] + f3.y) * di + bb.w) * di;
        float4 outv;
        __half2* op = (__half2*)&outv;
        op[0] = __floats2half2_rn(e0, e1);
        op[1] = __floats2half2_rn(e2, e3);
        op[2] = __floats2half2_rn(e4, e5);
        op[3] = __floats2half2_rn(e6, e7);
        *(float4*)&hh[(size_t)node * 64 + sub * 8] = outv;
    }
}

// R17 gather (frozen): g[i] = dinv[i]*(sum + hh[i]) = row i of S*h (f32).
__global__ __launch_bounds__(256) void k_gather_g(const int* __restrict__ off,
                                                  const int* __restrict__ csr,
                                                  const float* __restrict__ dinv,
                                                  const __half* __restrict__ hh,
                                                  float* __restrict__ gout, int n) {
    int node = blockIdx.x * 4 + (threadIdx.x >> 6);
    if (node >= n) return;
    int lane = threadIdx.x & 63;
    int g = lane >> 3, sub = lane & 7;
    int s0 = off[node], s1 = off[node + 1];
    float acc[8];
#pragma unroll
    for (int j = 0; j < 8; ++j) acc[j] = 0.f;

    if (s1 > s0) {
        int last = s1 - 1;
        int p0 = s0 + g, p1 = p0 + 8, p2 = p0 + 16, p3 = p0 + 24;
        int i0 = csr[p0 < s1 ? p0 : last];
        int i1 = csr[p1 < s1 ? p1 : last];
        int i2 = csr[p2 < s1 ? p2 : last];
        int i3 = csr[p3 < s1 ? p3 : last];
        float4 r0 = *(const float4*)&hh[(size_t)i0 * 64 + sub * 8];
        float4 r1 = *(const float4*)&hh[(size_t)i1 * 64 + sub * 8];
        float4 r2 = *(const float4*)&hh[(size_t)i2 * 64 + sub * 8];
        float4 r3 = *(const float4*)&hh[(size_t)i3 * 64 + sub * 8];
        float m0 = (p0 < s1) ? 1.f : 0.f;
        float m1 = (p1 < s1) ? 1.f : 0.f;
        float m2 = (p2 < s1) ? 1.f : 0.f;
        float m3 = (p3 < s1) ? 1.f : 0.f;
        ACC8(r0, m0);
        ACC8(r1, m1);
        ACC8(r2, m2);
        ACC8(r3, m3);
        for (int k = s0 + 32 + g; k < s1; k += 8) {  // rare (deg>32)
            int iv = csr[k];
            float4 rv = *(const float4*)&hh[(size_t)iv * 64 + sub * 8];
            ACC8(rv, 1.f);
        }
    }

#pragma unroll
    for (int j = 0; j < 8; ++j) {
        acc[j] += __shfl_xor(acc[j], 8, 64);
        acc[j] += __shfl_xor(acc[j], 16, 64);
        acc[j] += __shfl_xor(acc[j], 32, 64);
    }

    if (g == 0) {
        float4 sr = *(const float4*)&hh[(size_t)node * 64 + sub * 8];
        const __half2* sh = (const __half2*)&sr;
        float di = dinv[node];
        float2 f0 = __half22float2(sh[0]);
        float2 f1 = __half22float2(sh[1]);
        float2 f2 = __half22float2(sh[2]);
        float2 f3 = __half22float2(sh[3]);
        float o0 = (acc[0] + f0.x) * di;
        float o1 = (acc[1] + f0.y) * di;
        float o2 = (acc[2] + f1.x) * di;
        float o3 = (acc[3] + f1.y) * di;
        float o4 = (acc[4] + f2.x) * di;
        float o5 = (acc[5] + f2.y) * di;
        float o6 = (acc[6] + f3.x) * di;
        float o7 = (acc[7] + f3.y) * di;
        *(float4*)&gout[(size_t)node * 64 + sub * 8] = make_float4(o0, o1, o2, o3);
        *(float4*)&gout[(size_t)node * 64 + sub * 8 + 4] = make_float4(o4, o5, o6, o7);
    }
}

// mu|sig GEMM (MFMA) + bias + elu + pool stage-1 (LDS column reduce).
// P[64 rows][128 cols] staged in wc, then reduced per graph segment with
// boundary-flush atomics into sums (mu at [0,4096), sig at [4096,8192)).
__global__ __launch_bounds__(256) void k_mm_pool(const float* __restrict__ g,
                                                 const __half* __restrict__ Fmu,
                                                 const __half* __restrict__ Fsig,
                                                 const float* __restrict__ bmu,
                                                 const float* __restrict__ bsig,
                                                 const int* __restrict__ batch,
                                                 float* __restrict__ sums, int n) {
    __shared__ float wc[64 * 132];
    __shared__ int bs[64];
    const int tid = threadIdx.x;
    int l = tid & 63, wave = tid >> 6;
    int m0 = blockIdx.x * 64;
    int row_a = m0 + wave * 16 + (l & 15);
    if (row_a >= n) row_a = n - 1;
    int kg = l >> 4;

    f32x4 am[4], as[4];
#pragma unroll
    for (int ct = 0; ct < 4; ++ct) {
        am[ct] = (f32x4){0.f, 0.f, 0.f, 0.f};
        as[ct] = (f32x4){0.f, 0.f, 0.f, 0.f};
    }

    const float* gr = g + (size_t)row_a * 64 + kg * 8;
#pragma unroll
    for (int ks = 0; ks < 2; ++ks) {
        float4 xa = *(const float4*)(gr + ks * 32);
        float4 xb = *(const float4*)(gr + ks * 32 + 4);
        half8 a;
        a[0] = (_Float16)xa.x; a[1] = (_Float16)xa.y;
        a[2] = (_Float16)xa.z; a[3] = (_Float16)xa.w;
        a[4] = (_Float16)xb.x; a[5] = (_Float16)xb.y;
        a[6] = (_Float16)xb.z; a[7] = (_Float16)xb.w;
        const __half* fm = Fmu + ((size_t)(ks * 4) * 64 + l) * 8;
        const __half* fs = Fsig + ((size_t)(ks * 4) * 64 + l) * 8;
#pragma unroll
        for (int ct = 0; ct < 4; ++ct) {
            half8 bm = *(const half8*)(fm + ct * 512);
            half8 bv = *(const half8*)(fs + ct * 512);
            am[ct] = __builtin_amdgcn_mfma_f32_16x16x32_f16(a, bm, am[ct], 0, 0, 0);
            as[ct] = __builtin_amdgcn_mfma_f32_16x16x32_f16(a, bv, as[ct], 0, 0, 0);
        }
    }

    if (tid < 64) bs[tid] = (m0 + tid < n) ? batch[m0 + tid] : -1;

    int col = l & 15;
#pragma unroll
    for (int ct = 0; ct < 4; ++ct) {
        float bM = bmu[ct * 16 + col];
        float bS = bsig[ct * 16 + col];
#pragma unroll
        for (int r = 0; r < 4; ++r) {
            int rr = wave * 16 + kg * 4 + r;  // C/D row mapping
            wc[rr * 132 + ct * 16 + col] = elu1(am[ct][r] + bM);
            wc[rr * 132 + 64 + ct * 16 + col] = elu1(as[ct][r] + bS);
        }
    }
    __syncthreads();

    // Pool: thread (d, seg) reduces column d over rows [seg*32, seg*32+32),
    // flushing at graph boundaries (batch sorted).
    int d = tid & 127, seg = tid >> 7;
    int base = (d < 64) ? d : (64 * 64 - 64 + d);  // mu: g*64+d, sig: 4096+g*64+(d-64)
    float acc = 0.f;
    int gcur = -1;
    int r0 = seg * 32;
    for (int r = r0; r < r0 + 32; ++r) {
        int gb = bs[r];
        if (gb < 0) break;
        float v = wc[r * 132 + d];
        if (gb != gcur) {
            if (gcur >= 0) atomicAdd(&sums[base + gcur * 64], acc);
            acc = 0.f;
            gcur = gb;
        }
        acc += v;
    }
    if (gcur >= 0) atomicAdd(&sums[base + gcur * 64], acc);
}

// Pool stage 2: one thread per output element; cnt via binary search.
__global__ void k_pool_final(const float* __restrict__ sums,
                             const int* __restrict__ batch,
                             float* __restrict__ out, int n) {
    int i = blockIdx.x * blockDim.x + threadIdx.x;
    if (i >= 2 * N_GRAPHS * ZDIM) return;
    int g = (i >> 6) & 63;
    int lo = 0, hi = n;
    while (lo < hi) { int m = (lo + hi) >> 1; if (batch[m] < g) lo = m + 1; else hi = m; }
    int s = lo;
    lo = s; hi = n;
    while (lo < hi) { int m = (lo + hi) >> 1; if (batch[m] < g + 1) lo = m + 1; else hi = m; }
    float c = fmaxf((float)(lo - s), 1.0f);
    out[i] = sums[i] / c;
}

extern "C" void kernel_launch(void* const* d_in, const int* in_sizes, int n_in,
                              void* d_out, int out_size, void* d_ws, size_t ws_size,
                              hipStream_t stream) {
    const float* x    = (const float*)d_in[0];
    const int*   ei   = (const int*)d_in[1];
    const int*   batch= (const int*)d_in[2];
    // d_in[3] = num_graphs (scalar, known 64)
    const float* W1   = (const float*)d_in[4];
    const float* b1   = (const float*)d_in[5];
    const float* Wmu  = (const float*)d_in[6];
    const float* bmu  = (const float*)d_in[7];
    const float* Wsig = (const float*)d_in[8];
    const float* bsig = (const float*)d_in[9];
    float* out = (float*)d_out;

    const int n = in_sizes[0] / IN_DIM;   // 50000
    const int E = in_sizes[1] / 2;        // 800000
    const int* src = ei;
    const int* dst = ei + E;
    const int NSB = (n + SCAN_B - 1) / SCAN_B;  // scan blocks (49)

    float* ws = (float*)d_ws;
    size_t off_w = 0;
    int*   kc   = (int*)(ws + off_w); off_w += 50048;
    float* sums = ws + off_w; off_w += 8192;   // contiguous with kc: one memset
    float* dinv = ws + off_w; off_w += 50048;
    int*   offs = (int*)(ws + off_w); off_w += 50056;
    int*   bsum = (int*)(ws + off_w); off_w += 64;
    int*   rank = (int*)(ws + off_w); off_w += 800000;
    int*   csr  = (int*)(ws + off_w); off_w += 800000;
    off_w = (off_w + 15) & ~(size_t)15;
    __half* F1   = (__half*)(ws + off_w); off_w += 4096;  // 8192 halfs
    __half* Fmu  = (__half*)(ws + off_w); off_w += 2048;  // 4096 halfs
    __half* Fsig = (__half*)(ws + off_w); off_w += 2048;  // 4096 halfs
    const size_t BIG = (size_t)n * 64;
    __half* ts1h = (__half*)(ws + off_w); off_w += BIG / 2;  // fp16 (x@W1)*dinv
    __half* hh   = (__half*)(ws + off_w); off_w += BIG / 2;  // fp16 dinv*elu(layer1)
    float*  gbuf = ws + off_w; off_w += BIG;                 // f32 g = S*h

    const int gE  = (E + 255) / 256;
    const int gNW = (n + 3) / 4;      // one wave per node (R17 gather shape)
    const int NB  = (n + 63) / 64;    // 64-node GEMM tiles

    // CSR build + normalization (kc+sums zeroed in ONE contiguous memset)
    hipMemsetAsync(kc, 0, (50048 + 8192) * sizeof(int), stream);
    k_wfrag<<<32, 256, 0, stream>>>(W1, Wmu, Wsig, F1, Fmu, Fsig);
    k_count<<<gE, 256, 0, stream>>>(dst, kc, rank, E);
    k_scan1<<<NSB, SCAN_B, 0, stream>>>(kc, bsum, n);
    k_scan3<<<NSB, SCAN_B, 0, stream>>>(kc, bsum, offs, dinv, n, NSB);
    k_fill<<<gE, 256, 0, stream>>>(src, dst, rank, offs, csr, E);

    // layer 1: ts1h = fp16((x@W1)*dinv) via MFMA; hh = fp16(dinv*elu(...))
    k_mm1<<<NB, 256, 0, stream>>>(x, F1, dinv, ts1h, n);
    k_gather_hh<<<gNW, 256, 0, stream>>>(offs, csr, dinv, ts1h, b1, hh, n);

    // layers 2/3 shared gather: g = S*h (f32)
    k_gather_g<<<gNW, 256, 0, stream>>>(offs, csr, dinv, hh, gbuf, n);

    // mu|sig MFMA GEMM + bias + elu + fused pool stage-1
    k_mm_pool<<<NB, 256, 0, stream>>>(gbuf, Fmu, Fsig, bmu, bsig, batch, sums, n);
    k_pool_final<<<(2 * N_GRAPHS * ZDIM + 255) / 256, 256, 0, stream>>>(sums, batch, out, n);
}

// Round 6
// 217.073 us; speedup vs baseline: 1.2565x; 1.0144x over previous
//
#include <hip/hip_runtime.h>
#include <hip/hip_fp16.h>

// GCN encoder: 3x GCNConv (+self-loops, sym deg^-1/2 norm) + ELU + mean-pool.
// N=50000, E=800000, IN=128, HID=64, ZDIM=64, G=64. f32 in/out.
// R7: CSR gather. R8: parallel scan. R9: fp16 gathered operands.
// R11: atomic-free fill. R12/13: fused pool. R15: 8 rows in flight -> 252.6.
// R16: algebraic restructure S(hW)=(Sh)W -> one shared 64-dim gather. 249.6.
// R17: MLP gather decomposition, 32 rows in flight/wave -> 238.1.
// R18: XCD-split FAILED (272.7). R19: "issue-lean" FAILED (269.4) - it
//     actually DOUBLED per-row main-loop VALU (4-row batches vs 8-row).
//     Gathers frozen at R17 shape.
// R20: MFMA GEMMs (mfma_f32_16x16x32_f16, pre-swizzled weight frags,
//     same-k-permutation on A/B, verified C/D map) -> 220.2. WIN.
// R21: LAUNCH FUSION + f16 g-buffer. 12 -> 9 dispatches:
//     k_wfrag merged into k_count (independent); k_mm1 merged into k_fill
//     (both only need scan3); k_gather_g writes f16 gh2 directly (identical
//     rounding - mm_pool cast to f16 anyway), mm_pool A-frag = raw half8
//     load. Saves 3 launches + 12.8MB traffic + 16 cvt/wave.

#define IN_DIM 128
#define HID 64
#define ZDIM 64
#define N_GRAPHS 64
#define SCAN_B 1024

typedef _Float16 half8 __attribute__((ext_vector_type(8)));
typedef float f32x4 __attribute__((ext_vector_type(4)));

__device__ __forceinline__ float elu1(float x) {
    return x > 0.f ? x : expm1f(x);
}

// Accumulate 8 fp16 (held in a float4 raw register) with mask MV into acc[8].
#define ACC8(RV, MV) do { \
    const __half2* _hp = (const __half2*)&(RV); \
    float2 _f0 = __half22float2(_hp[0]); \
    float2 _f1 = __half22float2(_hp[1]); \
    float2 _f2 = __half22float2(_hp[2]); \
    float2 _f3 = __half22float2(_hp[3]); \
    acc[0] = fmaf((MV), _f0.x, acc[0]); \
    acc[1] = fmaf((MV), _f0.y, acc[1]); \
    acc[2] = fmaf((MV), _f1.x, acc[2]); \
    acc[3] = fmaf((MV), _f1.y, acc[3]); \
    acc[4] = fmaf((MV), _f2.x, acc[4]); \
    acc[5] = fmaf((MV), _f2.y, acc[5]); \
    acc[6] = fmaf((MV), _f3.x, acc[6]); \
    acc[7] = fmaf((MV), _f3.y, acc[7]); \
  } while (0)

// Fused: edge counting (rank/deg) + one-shot weight swizzle to frag order.
// Blocks [0,fillBlocks): rank[e] = atomicAdd(&kc[dst[e]],1).
// Blocks [fillBlocks, +32): F1/Fmu/Fsig fragment fill.
// F [ks][4ct][64l][8j] = f16(W[(ks*32+((l>>4)&3)*8+j)*64 + ct*16+(l&15)])
__global__ __launch_bounds__(256) void k_count_wfrag(const int* __restrict__ dst,
                                                     int* __restrict__ kc,
                                                     int* __restrict__ rank, int E,
                                                     const float* __restrict__ W1,
                                                     const float* __restrict__ Wmu,
                                                     const float* __restrict__ Wsig,
                                                     __half* __restrict__ F1,
                                                     __half* __restrict__ Fmu,
                                                     __half* __restrict__ Fsig,
                                                     int fillBlocks) {
    if ((int)blockIdx.x < fillBlocks) {
        int e = blockIdx.x * 256 + threadIdx.x;
        if (e < E) rank[e] = atomicAdd(&kc[dst[e]], 1);
        return;
    }
    int e = (blockIdx.x - fillBlocks) * 256 + threadIdx.x;
    if (e < 8192) {
        int j = e & 7, l = (e >> 3) & 63, ct = (e >> 9) & 3, ks = e >> 11;
        F1[e] = __float2half(W1[(ks * 32 + ((l >> 4) & 3) * 8 + j) * 64 + ct * 16 + (l & 15)]);
    }
    if (e < 4096) {
        int j = e & 7, l = (e >> 3) & 63, ct = (e >> 9) & 3, ks = e >> 11;
        int widx = (ks * 32 + ((l >> 4) & 3) * 8 + j) * 64 + ct * 16 + (l & 15);
        Fmu[e] = __float2half(Wmu[widx]);
        Fsig[e] = __float2half(Wsig[widx]);
    }
}

// S1: per-block sum of kc -> bsum[blk]
__global__ __launch_bounds__(SCAN_B) void k_scan1(const int* __restrict__ kc,
                                                  int* __restrict__ bsum, int n) {
    __shared__ int wpart[16];
    int tid = threadIdx.x, lane = tid & 63, w = tid >> 6;
    int i = blockIdx.x * SCAN_B + tid;
    int v = (i < n) ? kc[i] : 0;
#pragma unroll
    for (int d = 1; d < 64; d <<= 1) v += __shfl_xor(v, d, 64);
    if (lane == 0) wpart[w] = v;
    __syncthreads();
    if (tid < 16) {
        int t = wpart[tid];
#pragma unroll
        for (int d = 1; d < 16; d <<= 1) t += __shfl_xor(t, d, 64);
        if (tid == 0) bsum[blockIdx.x] = t;
    }
}

// S3: each block re-scans bsum in-register (nb<=64) for its base, then
// offs[i+1] = inclusive prefix, dinv[i] = 1/sqrt(1+kc[i]).
__global__ __launch_bounds__(SCAN_B) void k_scan3(const int* __restrict__ kc,
                                                  const int* __restrict__ bsum,
                                                  int* __restrict__ offs,
                                                  float* __restrict__ dinv,
                                                  int n, int nb) {
    __shared__ int wsum[16];
    __shared__ int sbase;
    int tid = threadIdx.x, lane = tid & 63, w = tid >> 6;
    if (tid < 64) {  // wave 0: exclusive prefix of bsum at blockIdx.x
        int v = (tid < nb) ? bsum[tid] : 0;
        int s = v;
#pragma unroll
        for (int d = 1; d < 64; d <<= 1) {
            int u = __shfl_up(s, d, 64);
            if (tid >= d) s += u;
        }
        if (tid == blockIdx.x) sbase = s - v;
    }
    int i = blockIdx.x * SCAN_B + tid;
    int v = (i < n) ? kc[i] : 0;
    int s = v;
#pragma unroll
    for (int d = 1; d < 64; d <<= 1) {
        int u = __shfl_up(s, d, 64);
        if (lane >= d) s += u;
    }
    if (lane == 63) wsum[w] = s;
    __syncthreads();
    if (tid < 16) {
        int t = wsum[tid];
#pragma unroll
        for (int d = 1; d < 16; d <<= 1) {
            int u = __shfl_up(t, d, 64);
            if (tid >= d) t += u;
        }
        wsum[tid] = t;
    }
    __syncthreads();
    int base = sbase + ((w == 0) ? 0 : wsum[w - 1]);
    if (i < n) {
        offs[i + 1] = base + s;
        dinv[i] = 1.0f / sqrtf(1.0f + (float)v);
        if (i == 0) offs[0] = 0;
    }
}

// Fused: atomic-free CSR fill + MFMA mm1 (both depend only on scan3/count).
// Blocks [0,fillBlocks): csr[offs[dst]+rank] = src.
// Blocks [fillBlocks, +NB): ts1h = fp16((x @ W1) * dinv) via MFMA;
//   wave = 16 rows, 4 ct-tiles x 4 ks, A-frag = 8 f32->f16 casts,
//   B-frag = one 16B load from F1; C/D: col=lane&15, row=(lane>>4)*4+r.
__global__ __launch_bounds__(256) void k_fill_mm1(const int* __restrict__ src,
                                                  const int* __restrict__ dst,
                                                  const int* __restrict__ rank,
                                                  const int* __restrict__ offs,
                                                  int* __restrict__ csr, int E,
                                                  const float* __restrict__ x,
                                                  const __half* __restrict__ F1,
                                                  const float* __restrict__ dinv,
                                                  __half* __restrict__ ts1h, int n,
                                                  int fillBlocks) {
    if ((int)blockIdx.x < fillBlocks) {
        int e = blockIdx.x * 256 + threadIdx.x;
        if (e < E) csr[offs[dst[e]] + rank[e]] = src[e];
        return;
    }
    int bid = blockIdx.x - fillBlocks;
    int l = threadIdx.x & 63;
    int wave = threadIdx.x >> 6;
    int m0 = bid * 64 + wave * 16;
    int row_a = m0 + (l & 15);
    if (row_a >= n) row_a = n - 1;  // clamp loads; stores guarded
    int kg = l >> 4;

    f32x4 acc0 = {0.f, 0.f, 0.f, 0.f};
    f32x4 acc1 = acc0, acc2 = acc0, acc3 = acc0;

    const float* xr = x + (size_t)row_a * IN_DIM + kg * 8;
#pragma unroll
    for (int ks = 0; ks < 4; ++ks) {
        float4 xa = *(const float4*)(xr + ks * 32);
        float4 xb = *(const float4*)(xr + ks * 32 + 4);
        half8 a;
        a[0] = (_Float16)xa.x; a[1] = (_Float16)xa.y;
        a[2] = (_Float16)xa.z; a[3] = (_Float16)xa.w;
        a[4] = (_Float16)xb.x; a[5] = (_Float16)xb.y;
        a[6] = (_Float16)xb.z; a[7] = (_Float16)xb.w;
        const __half* fb = F1 + ((size_t)(ks * 4) * 64 + l) * 8;
        half8 b0 = *(const half8*)(fb);
        half8 b1 = *(const half8*)(fb + 512);
        half8 b2 = *(const half8*)(fb + 1024);
        half8 b3 = *(const half8*)(fb + 1536);
        acc0 = __builtin_amdgcn_mfma_f32_16x16x32_f16(a, b0, acc0, 0, 0, 0);
        acc1 = __builtin_amdgcn_mfma_f32_16x16x32_f16(a, b1, acc1, 0, 0, 0);
        acc2 = __builtin_amdgcn_mfma_f32_16x16x32_f16(a, b2, acc2, 0, 0, 0);
        acc3 = __builtin_amdgcn_mfma_f32_16x16x32_f16(a, b3, acc3, 0, 0, 0);
    }
    int col = l & 15;
#pragma unroll
    for (int r = 0; r < 4; ++r) {
        int row = m0 + kg * 4 + r;  // C/D: row=(lane>>4)*4+reg, col=lane&15
        if (row < n) {
            float di = dinv[row];
            __half* p = &ts1h[(size_t)row * 64 + col];
            p[0]  = __float2half(acc0[r] * di);
            p[16] = __float2half(acc1[r] * di);
            p[32] = __float2half(acc2[r] * di);
            p[48] = __float2half(acc3[r] * di);
        }
    }
}

// R17 gather (frozen): hh[i] = fp16(dinv * elu(dinv*(sum+self) + b1)).
// Wave = node. group g=lane>>3 owns a row, chunk sub=lane&7 owns 16B of it.
// 4 preloaded batches = 32 rows in flight; clamped slots alias last row's
// line (L1 hit). Tail loop for deg>32 (P~1e-4). 3x shfl_xor group combine.
__global__ __launch_bounds__(256) void k_gather_hh(const int* __restrict__ off,
                                                   const int* __restrict__ csr,
                                                   const float* __restrict__ dinv,
                                                   const __half* __restrict__ ts,
                                                   const float* __restrict__ b1,
                                                   __half* __restrict__ hh, int n) {
    int node = blockIdx.x * 4 + (threadIdx.x >> 6);
    if (node >= n) return;
    int lane = threadIdx.x & 63;
    int g = lane >> 3, sub = lane & 7;
    int s0 = off[node], s1 = off[node + 1];
    float acc[8];
#pragma unroll
    for (int j = 0; j < 8; ++j) acc[j] = 0.f;

    if (s1 > s0) {
        int last = s1 - 1;
        int p0 = s0 + g, p1 = p0 + 8, p2 = p0 + 16, p3 = p0 + 24;
        int i0 = csr[p0 < s1 ? p0 : last];
        int i1 = csr[p1 < s1 ? p1 : last];
        int i2 = csr[p2 < s1 ? p2 : last];
        int i3 = csr[p3 < s1 ? p3 : last];
        float4 r0 = *(const float4*)&ts[(size_t)i0 * 64 + sub * 8];
        float4 r1 = *(const float4*)&ts[(size_t)i1 * 64 + sub * 8];
        float4 r2 = *(const float4*)&ts[(size_t)i2 * 64 + sub * 8];
        float4 r3 = *(const float4*)&ts[(size_t)i3 * 64 + sub * 8];
        float m0 = (p0 < s1) ? 1.f : 0.f;
        float m1 = (p1 < s1) ? 1.f : 0.f;
        float m2 = (p2 < s1) ? 1.f : 0.f;
        float m3 = (p3 < s1) ? 1.f : 0.f;
        ACC8(r0, m0);
        ACC8(r1, m1);
        ACC8(r2, m2);
        ACC8(r3, m3);
        for (int k = s0 + 32 + g; k < s1; k += 8) {  // rare (deg>32)
            int iv = csr[k];
            float4 rv = *(const float4*)&ts[(size_t)iv * 64 + sub * 8];
            ACC8(rv, 1.f);
        }
    }

#pragma unroll
    for (int j = 0; j < 8; ++j) {
        acc[j] += __shfl_xor(acc[j], 8, 64);
        acc[j] += __shfl_xor(acc[j], 16, 64);
        acc[j] += __shfl_xor(acc[j], 32, 64);
    }

    if (g == 0) {
        float4 sr = *(const float4*)&ts[(size_t)node * 64 + sub * 8];
        const __half2* sh = (const __half2*)&sr;
        float di = dinv[node];
        const float4* b4 = (const float4*)b1;
        float4 ba = b4[sub * 2], bb = b4[sub * 2 + 1];
        float2 f0 = __half22float2(sh[0]);
        float2 f1 = __half22float2(sh[1]);
        float2 f2 = __half22float2(sh[2]);
        float2 f3 = __half22float2(sh[3]);
        float e0 = elu1((acc[0] + f0.x) * di + ba.x) * di;
        float e1 = elu1((acc[1] + f0.y) * di + ba.y) * di;
        float e2 = elu1((acc[2] + f1.x) * di + ba.z) * di;
        float e3 = elu1((acc[3] + f1.y) * di + ba.w) * di;
        float e4 = elu1((acc[4] + f2.x) * di + bb.x) * di;
        float e5 = elu1((acc[5] + f2.y) * di + bb.y) * di;
        float e6 = elu1((acc[6] + f3.x) * di + bb.z) * di;
        float e7 = elu1((acc[7] + f3.y) * di + bb.w) * di;
        float4 outv;
        __half2* op = (__half2*)&outv;
        op[0] = __floats2half2_rn(e0, e1);
        op[1] = __floats2half2_rn(e2, e3);
        op[2] = __floats2half2_rn(e4, e5);
        op[3] = __floats2half2_rn(e6, e7);
        *(float4*)&hh[(size_t)node * 64 + sub * 8] = outv;
    }
}

// R17 gather (frozen shape): gh2[i] = f16(dinv[i]*(sum + hh[i])) - the f16
// cast is identical to mm_pool's old A-frag cast, just moved to producer.
__global__ __launch_bounds__(256) void k_gather_g(const int* __restrict__ off,
                                                  const int* __restrict__ csr,
                                                  const float* __restrict__ dinv,
                                                  const __half* __restrict__ hh,
                                                  __half* __restrict__ gh2, int n) {
    int node = blockIdx.x * 4 + (threadIdx.x >> 6);
    if (node >= n) return;
    int lane = threadIdx.x & 63;
    int g = lane >> 3, sub = lane & 7;
    int s0 = off[node], s1 = off[node + 1];
    float acc[8];
#pragma unroll
    for (int j = 0; j < 8; ++j) acc[j] = 0.f;

    if (s1 > s0) {
        int last = s1 - 1;
        int p0 = s0 + g, p1 = p0 + 8, p2 = p0 + 16, p3 = p0 + 24;
        int i0 = csr[p0 < s1 ? p0 : last];
        int i1 = csr[p1 < s1 ? p1 : last];
        int i2 = csr[p2 < s1 ? p2 : last];
        int i3 = csr[p3 < s1 ? p3 : last];
        float4 r0 = *(const float4*)&hh[(size_t)i0 * 64 + sub * 8];
        float4 r1 = *(const float4*)&hh[(size_t)i1 * 64 + sub * 8];
        float4 r2 = *(const float4*)&hh[(size_t)i2 * 64 + sub * 8];
        float4 r3 = *(const float4*)&hh[(size_t)i3 * 64 + sub * 8];
        float m0 = (p0 < s1) ? 1.f : 0.f;
        float m1 = (p1 < s1) ? 1.f : 0.f;
        float m2 = (p2 < s1) ? 1.f : 0.f;
        float m3 = (p3 < s1) ? 1.f : 0.f;
        ACC8(r0, m0);
        ACC8(r1, m1);
        ACC8(r2, m2);
        ACC8(r3, m3);
        for (int k = s0 + 32 + g; k < s1; k += 8) {  // rare (deg>32)
            int iv = csr[k];
            float4 rv = *(const float4*)&hh[(size_t)iv * 64 + sub * 8];
            ACC8(rv, 1.f);
        }
    }

#pragma unroll
    for (int j = 0; j < 8; ++j) {
        acc[j] += __shfl_xor(acc[j], 8, 64);
        acc[j] += __shfl_xor(acc[j], 16, 64);
        acc[j] += __shfl_xor(acc[j], 32, 64);
    }

    if (g == 0) {
        float4 sr = *(const float4*)&hh[(size_t)node * 64 + sub * 8];
        const __half2* sh = (const __half2*)&sr;
        float di = dinv[node];
        float2 f0 = __half22float2(sh[0]);
        float2 f1 = __half22float2(sh[1]);
        float2 f2 = __half22float2(sh[2]);
        float2 f3 = __half22float2(sh[3]);
        float4 outv;
        __half2* op = (__half2*)&outv;
        op[0] = __floats2half2_rn((acc[0] + f0.x) * di, (acc[1] + f0.y) * di);
        op[1] = __floats2half2_rn((acc[2] + f1.x) * di, (acc[3] + f1.y) * di);
        op[2] = __floats2half2_rn((acc[4] + f2.x) * di, (acc[5] + f2.y) * di);
        op[3] = __floats2half2_rn((acc[6] + f3.x) * di, (acc[7] + f3.y) * di);
        *(float4*)&gh2[(size_t)node * 64 + sub * 8] = outv;
    }
}

// mu|sig GEMM (MFMA, f16 A direct from gh2) + bias + elu + pool stage-1
// (LDS column reduce with boundary-flush atomics into sums).
__global__ __launch_bounds__(256) void k_mm_pool(const __half* __restrict__ gh2,
                                                 const __half* __restrict__ Fmu,
                                                 const __half* __restrict__ Fsig,
                                                 const float* __restrict__ bmu,
                                                 const float* __restrict__ bsig,
                                                 const int* __restrict__ batch,
                                                 float* __restrict__ sums, int n) {
    __shared__ float wc[64 * 132];
    __shared__ int bs[64];
    const int tid = threadIdx.x;
    int l = tid & 63, wave = tid >> 6;
    int m0 = blockIdx.x * 64;
    int row_a = m0 + wave * 16 + (l & 15);
    if (row_a >= n) row_a = n - 1;
    int kg = l >> 4;

    f32x4 am[4], as[4];
#pragma unroll
    for (int ct = 0; ct < 4; ++ct) {
        am[ct] = (f32x4){0.f, 0.f, 0.f, 0.f};
        as[ct] = (f32x4){0.f, 0.f, 0.f, 0.f};
    }

    const __half* gr = gh2 + (size_t)row_a * 64 + kg * 8;
#pragma unroll
    for (int ks = 0; ks < 2; ++ks) {
        half8 a = *(const half8*)(gr + ks * 32);
        const __half* fm = Fmu + ((size_t)(ks * 4) * 64 + l) * 8;
        const __half* fs = Fsig + ((size_t)(ks * 4) * 64 + l) * 8;
#pragma unroll
        for (int ct = 0; ct < 4; ++ct) {
            half8 bm = *(const half8*)(fm + ct * 512);
            half8 bv = *(const half8*)(fs + ct * 512);
            am[ct] = __builtin_amdgcn_mfma_f32_16x16x32_f16(a, bm, am[ct], 0, 0, 0);
            as[ct] = __builtin_amdgcn_mfma_f32_16x16x32_f16(a, bv, as[ct], 0, 0, 0);
        }
    }

    if (tid < 64) bs[tid] = (m0 + tid < n) ? batch[m0 + tid] : -1;

    int col = l & 15;
#pragma unroll
    for (int ct = 0; ct < 4; ++ct) {
        float bM = bmu[ct * 16 + col];
        float bS = bsig[ct * 16 + col];
#pragma unroll
        for (int r = 0; r < 4; ++r) {
            int rr = wave * 16 + kg * 4 + r;  // C/D row mapping
            wc[rr * 132 + ct * 16 + col] = elu1(am[ct][r] + bM);
            wc[rr * 132 + 64 + ct * 16 + col] = elu1(as[ct][r] + bS);
        }
    }
    __syncthreads();

    // Pool: thread (d, seg) reduces column d over rows [seg*32, seg*32+32),
    // flushing at graph boundaries (batch sorted).
    int d = tid & 127, seg = tid >> 7;
    int base = (d < 64) ? d : (64 * 64 - 64 + d);  // mu: g*64+d, sig: 4096+g*64+(d-64)
    float acc = 0.f;
    int gcur = -1;
    int r0 = seg * 32;
    for (int r = r0; r < r0 + 32; ++r) {
        int gb = bs[r];
        if (gb < 0) break;
        float v = wc[r * 132 + d];
        if (gb != gcur) {
            if (gcur >= 0) atomicAdd(&sums[base + gcur * 64], acc);
            acc = 0.f;
            gcur = gb;
        }
        acc += v;
    }
    if (gcur >= 0) atomicAdd(&sums[base + gcur * 64], acc);
}

// Pool stage 2: one thread per output element; cnt via binary search.
__global__ void k_pool_final(const float* __restrict__ sums,
                             const int* __restrict__ batch,
                             float* __restrict__ out, int n) {
    int i = blockIdx.x * blockDim.x + threadIdx.x;
    if (i >= 2 * N_GRAPHS * ZDIM) return;
    int g = (i >> 6) & 63;
    int lo = 0, hi = n;
    while (lo < hi) { int m = (lo + hi) >> 1; if (batch[m] < g) lo = m + 1; else hi = m; }
    int s = lo;
    lo = s; hi = n;
    while (lo < hi) { int m = (lo + hi) >> 1; if (batch[m] < g + 1) lo = m + 1; else hi = m; }
    float c = fmaxf((float)(lo - s), 1.0f);
    out[i] = sums[i] / c;
}

extern "C" void kernel_launch(void* const* d_in, const int* in_sizes, int n_in,
                              void* d_out, int out_size, void* d_ws, size_t ws_size,
                              hipStream_t stream) {
    const float* x    = (const float*)d_in[0];
    const int*   ei   = (const int*)d_in[1];
    const int*   batch= (const int*)d_in[2];
    // d_in[3] = num_graphs (scalar, known 64)
    const float* W1   = (const float*)d_in[4];
    const float* b1   = (const float*)d_in[5];
    const float* Wmu  = (const float*)d_in[6];
    const float* bmu  = (const float*)d_in[7];
    const float* Wsig = (const float*)d_in[8];
    const float* bsig = (const float*)d_in[9];
    float* out = (float*)d_out;

    const int n = in_sizes[0] / IN_DIM;   // 50000
    const int E = in_sizes[1] / 2;        // 800000
    const int* src = ei;
    const int* dst = ei + E;
    const int NSB = (n + SCAN_B - 1) / SCAN_B;  // scan blocks (49)

    float* ws = (float*)d_ws;
    size_t off_w = 0;
    int*   kc   = (int*)(ws + off_w); off_w += 50048;
    float* sums = ws + off_w; off_w += 8192;   // contiguous with kc: one memset
    float* dinv = ws + off_w; off_w += 50048;
    int*   offs = (int*)(ws + off_w); off_w += 50056;
    int*   bsum = (int*)(ws + off_w); off_w += 64;
    int*   rank = (int*)(ws + off_w); off_w += 800000;
    int*   csr  = (int*)(ws + off_w); off_w += 800000;
    off_w = (off_w + 15) & ~(size_t)15;
    __half* F1   = (__half*)(ws + off_w); off_w += 4096;  // 8192 halfs
    __half* Fmu  = (__half*)(ws + off_w); off_w += 2048;  // 4096 halfs
    __half* Fsig = (__half*)(ws + off_w); off_w += 2048;  // 4096 halfs
    const size_t BIG = (size_t)n * 64;
    __half* ts1h = (__half*)(ws + off_w); off_w += BIG / 2;  // fp16 (x@W1)*dinv
    __half* hh   = (__half*)(ws + off_w); off_w += BIG / 2;  // fp16 dinv*elu(layer1)
    __half* gh2  = (__half*)(ws + off_w); off_w += BIG / 2;  // fp16 g = S*h

    const int gE  = (E + 255) / 256;  // 3125
    const int gNW = (n + 3) / 4;      // one wave per node (R17 gather shape)
    const int NB  = (n + 63) / 64;    // 64-node GEMM tiles

    // CSR build + normalization (kc+sums zeroed in ONE contiguous memset)
    hipMemsetAsync(kc, 0, (50048 + 8192) * sizeof(int), stream);
    k_count_wfrag<<<gE + 32, 256, 0, stream>>>(dst, kc, rank, E,
                                               W1, Wmu, Wsig, F1, Fmu, Fsig, gE);
    k_scan1<<<NSB, SCAN_B, 0, stream>>>(kc, bsum, n);
    k_scan3<<<NSB, SCAN_B, 0, stream>>>(kc, bsum, offs, dinv, n, NSB);

    // CSR fill + layer-1 MFMA GEMM (independent; both need only scan3)
    k_fill_mm1<<<gE + NB, 256, 0, stream>>>(src, dst, rank, offs, csr, E,
                                            x, F1, dinv, ts1h, n, gE);

    // layer 1 gather: hh = fp16(dinv*elu(S(xW1)+b1))
    k_gather_hh<<<gNW, 256, 0, stream>>>(offs, csr, dinv, ts1h, b1, hh, n);

    // layers 2/3 shared gather: gh2 = f16(S*h)
    k_gather_g<<<gNW, 256, 0, stream>>>(offs, csr, dinv, hh, gh2, n);

    // mu|sig MFMA GEMM + bias + elu + fused pool stage-1
    k_mm_pool<<<NB, 256, 0, stream>>>(gh2, Fmu, Fsig, bmu, bsig, batch, sums, n);
    k_pool_final<<<(2 * N_GRAPHS * ZDIM + 255) / 256, 256, 0, stream>>>(sums, batch, out, n);
}